// Round 2
// baseline (146.235 us; speedup 1.0000x reference)
//
#include <hip/hip_runtime.h>

#define N_    4
#define CIN   64
#define COUT  64
#define H_    128
#define W_    128
#define HO_   128
#define WO_   128
#define K2_   9

// One-shot weight transpose: w[co][ci][k] -> wt[k][ci][co] so the main
// kernel's per-tap W staging is a coalesced float4 stream.
__global__ void DeformConv2d_wtrans(const float* __restrict__ w,
                                    float* __restrict__ wt) {
    int i = blockIdx.x * 256 + threadIdx.x;           // over 36864
    if (i < COUT * CIN * K2_) {
        int k  = i % K2_;
        int ci = (i / K2_) % CIN;
        int co = i / (K2_ * CIN);
        wt[(k * CIN + ci) * COUT + co] = w[i];
    }
}

// Block = 64 c_out x (4 ho x 16 wo) pixel tile. px = py*16+pxx.
template <bool USE_WS>
__global__ __launch_bounds__(256, 4) void DeformConv2d_kernel(
    const float* __restrict__ x,       // [N,CIN,H,W]
    const float* __restrict__ offset,  // [N,2*K2,HO,WO]
    const float* __restrict__ mask,    // [N,K2,HO,WO]
    const float* __restrict__ weight,  // [COUT,CIN,KH,KW]
    const float* __restrict__ wt,      // [K2,CIN,COUT] (if USE_WS)
    float* __restrict__ out)           // [N,COUT,HO,WO]
{
    __shared__ float W_lds[CIN * COUT];   // [ci][co]
    __shared__ float S_lds[CIN * 64];     // [ci][px]
    __shared__ float cfy[64], cfx[64], cm[64];
    __shared__ int   cy0[64], cx0[64];

    const int tid = threadIdx.x;

    // Bijective XCD chunk swizzle: 1024 blocks, 8 XCDs, 128 per chunk.
    // Same-XCD blocks get contiguous swz -> half-image footprint (~2.3MB < 4MiB L2).
    const int raw = blockIdx.x;
    const int swz = (raw & 7) * 128 + (raw >> 3);
    const int n   = swz >> 8;              // 0..3
    const int r   = swz & 255;
    const int hb  = (r >> 3) << 2;         // 0..124 step 4
    const int wb  = (r & 7) << 4;          // 0..112 step 16

    const int tr = tid >> 4;               // 0..15 -> co group (co = tr*4+j)
    const int tc = tid & 15;               // 0..15 -> px group (px = tc*4+i)

    float acc[4][4];
#pragma unroll
    for (int j = 0; j < 4; ++j)
#pragma unroll
        for (int i = 0; i < 4; ++i) acc[j][i] = 0.f;

    for (int k = 0; k < K2_; ++k) {
        __syncthreads();   // previous tap's GEMM done reading LDS

        // ---- phase 1: per-pixel bilinear coords + W_k staging ----
        if (tid < 64) {
            const int px  = tid;
            const int ho  = hb + (px >> 4);
            const int wo  = wb + (px & 15);
            const int ki = k / 3, kj = k % 3;
            const float dy = offset[((n * (2 * K2_) + 2 * k)     * HO_ + ho) * WO_ + wo];
            const float dx = offset[((n * (2 * K2_) + 2 * k + 1) * HO_ + ho) * WO_ + wo];
            const float m  = mask  [((n * K2_       + k)         * HO_ + ho) * WO_ + wo];
            const float yy = (float)(ho - 1 + ki) + dy;
            const float xx = (float)(wo - 1 + kj) + dx;
            const float y0f = floorf(yy), x0f = floorf(xx);
            cy0[px] = (int)y0f;
            cx0[px] = (int)x0f;
            cfy[px] = yy - y0f;
            cfx[px] = xx - x0f;
            cm[px]  = m;
        }
        if (USE_WS) {
            const float4* wk = (const float4*)(wt + k * CIN * COUT);
#pragma unroll
            for (int e = 0; e < 4; ++e) {           // 1024 float4 / 256 thr
                int i4 = e * 256 + tid;
                ((float4*)W_lds)[i4] = wk[i4];
            }
        } else {
#pragma unroll
            for (int e = 0; e < 16; ++e) {
                int i  = e * 256 + tid;
                int ci = i >> 6, co = i & 63;
                W_lds[ci * 64 + co] = weight[(co * CIN + ci) * K2_ + k];
            }
        }
        __syncthreads();

        // ---- phase 2: sample S_k[ci][px] = bilinear(x)*mask ----
        // wave w, iter e handles ci = e*4 + w for all 64 px (one ci per wave).
#pragma unroll
        for (int e = 0; e < 16; ++e) {
            int i  = e * 256 + tid;
            int ci = i >> 6, px = i & 63;
            int   y0 = cy0[px], x0 = cx0[px];
            float fy = cfy[px], fx = cfx[px], m = cm[px];
            const float* xc = x + (size_t)(n * CIN + ci) * (H_ * W_);
            bool yv0 = (y0 >= 0)  && (y0 < H_);
            bool yv1 = (y0 >= -1) && (y0 < H_ - 1);
            bool xv0 = (x0 >= 0)  && (x0 < W_);
            bool xv1 = (x0 >= -1) && (x0 < W_ - 1);
            float v00 = (yv0 && xv0) ? xc[y0 * W_ + x0]           : 0.f;
            float v01 = (yv0 && xv1) ? xc[y0 * W_ + x0 + 1]       : 0.f;
            float v10 = (yv1 && xv0) ? xc[(y0 + 1) * W_ + x0]     : 0.f;
            float v11 = (yv1 && xv1) ? xc[(y0 + 1) * W_ + x0 + 1] : 0.f;
            float v = (v00 * (1.f - fy) + v10 * fy) * (1.f - fx)
                    + (v01 * (1.f - fy) + v11 * fy) * fx;
            S_lds[ci * 64 + px] = v * m;
        }
        __syncthreads();

        // ---- phase 3: 64x64x64 mini-GEMM, 4x4 per thread ----
#pragma unroll 8
        for (int ci = 0; ci < CIN; ++ci) {
            const float4 a = *(const float4*)&W_lds[ci * 64 + tr * 4];
            const float4 b = *(const float4*)&S_lds[ci * 64 + tc * 4];
            acc[0][0] += a.x * b.x; acc[0][1] += a.x * b.y;
            acc[0][2] += a.x * b.z; acc[0][3] += a.x * b.w;
            acc[1][0] += a.y * b.x; acc[1][1] += a.y * b.y;
            acc[1][2] += a.y * b.z; acc[1][3] += a.y * b.w;
            acc[2][0] += a.z * b.x; acc[2][1] += a.z * b.y;
            acc[2][2] += a.z * b.z; acc[2][3] += a.z * b.w;
            acc[3][0] += a.w * b.x; acc[3][1] += a.w * b.y;
            acc[3][2] += a.w * b.z; acc[3][3] += a.w * b.w;
        }
    }

    // ---- epilogue: coalesced float4 stores (4 px of one tile row) ----
    const int co0  = tr * 4;
    const int hoE  = hb + (tc >> 2);
    const int woE  = wb + (tc & 3) * 4;
#pragma unroll
    for (int j = 0; j < 4; ++j) {
        float4 v;
        v.x = acc[j][0]; v.y = acc[j][1]; v.z = acc[j][2]; v.w = acc[j][3];
        *(float4*)&out[((size_t)(n * COUT + co0 + j) * HO_ + hoE) * WO_ + woE] = v;
    }
}

extern "C" void kernel_launch(void* const* d_in, const int* in_sizes, int n_in,
                              void* d_out, int out_size, void* d_ws, size_t ws_size,
                              hipStream_t stream) {
    const float* x      = (const float*)d_in[0];
    const float* offset = (const float*)d_in[1];
    const float* mask   = (const float*)d_in[2];
    const float* weight = (const float*)d_in[3];
    float* out = (float*)d_out;

    const size_t wt_bytes = (size_t)K2_ * CIN * COUT * sizeof(float);
    if (ws_size >= wt_bytes) {
        float* wt = (float*)d_ws;
        DeformConv2d_wtrans<<<(COUT * CIN * K2_ + 255) / 256, 256, 0, stream>>>(weight, wt);
        DeformConv2d_kernel<true><<<1024, 256, 0, stream>>>(x, offset, mask, weight, wt, out);
    } else {
        DeformConv2d_kernel<false><<<1024, 256, 0, stream>>>(x, offset, mask, weight, nullptr, out);
    }
}

// Round 3
// 114.090 us; speedup vs baseline: 1.2817x; 1.2817x over previous
//
#include <hip/hip_runtime.h>

#define N_    4
#define CIN   64
#define COUT  64
#define H_    128
#define W_    128
#define HO_   128
#define WO_   128
#define K2_   9
#define SLD   68   // S_lds leading dim (floats): 16B-aligned float4 rows, banks spread

// One-shot weight transpose: w[co][ci][k] -> wt[k][ci][co].
__global__ void DeformConv2d_wtrans(const float* __restrict__ w,
                                    float* __restrict__ wt) {
    int i = blockIdx.x * 256 + threadIdx.x;
    if (i < COUT * CIN * K2_) {
        int k  = i % K2_;
        int ci = (i / K2_) % CIN;
        int co = i / (K2_ * CIN);
        wt[(k * CIN + ci) * COUT + co] = w[i];
    }
}

// One-shot NCHW -> NHWC: xt[n][y][x][c] = x[n][c][y][x]. LDS-tiled.
__global__ __launch_bounds__(256) void DeformConv2d_nhwc(const float* __restrict__ x,
                                                         float* __restrict__ xt) {
    __shared__ float tile[64][17];
    const int b  = blockIdx.x;            // 4096 = n(4) * y(128) * xstrip(8)
    const int xs = (b & 7) << 4;
    const int y  = (b >> 3) & 127;
    const int n  = b >> 10;
    const int t  = threadIdx.x;
    const int xi = t & 15, c0 = t >> 4;
#pragma unroll
    for (int p = 0; p < 4; ++p) {
        int c = c0 + p * 16;
        tile[c][xi] = x[((size_t)(n * 64 + c) * 128 + y) * 128 + xs + xi];
    }
    __syncthreads();
    const int cw = t & 63, x4 = t >> 6;
#pragma unroll
    for (int q = 0; q < 4; ++q) {
        int xw = q * 4 + x4;
        xt[((size_t)((n * 128 + y) * 128) + xs + xw) * 64 + cw] = tile[cw][xw];
    }
}

// Block = 64 c_out x (4 ho x 16 wo) pixel tile.
template <bool USE_WS, bool USE_NHWC>
__global__ __launch_bounds__(256, 4) void DeformConv2d_kernel(
    const float* __restrict__ x,       // [N,CIN,H,W]
    const float* __restrict__ offset,  // [N,2*K2,HO,WO]
    const float* __restrict__ mask,    // [N,K2,HO,WO]
    const float* __restrict__ weight,  // [COUT,CIN,KH,KW]
    const float* __restrict__ wt,      // [K2,CIN,COUT]
    const float* __restrict__ xt,      // [N,H,W,CIN] (NHWC)
    float* __restrict__ out)           // [N,COUT,HO,WO]
{
    __shared__ float  W_lds[CIN * COUT];     // [ci][co], LD 64
    __shared__ float  S_lds[CIN * SLD];      // [ci][px], LD 68
    __shared__ float4 cpA[64];               // {fy, fx, m, bitcast(validmask)}
    __shared__ int    cpB[64];               // obase = (y0*W + x0)*64
    __shared__ int    cy0[64], cx0[64];      // for non-NHWC fallback

    const int tid = threadIdx.x;

    // Bijective XCD chunk swizzle: 1024 blocks, 8 XCDs, 128 per chunk.
    const int raw = blockIdx.x;
    const int swz = (raw & 7) * 128 + (raw >> 3);
    const int n   = swz >> 8;
    const int r   = swz & 255;
    const int hb  = (r >> 3) << 2;         // 0..124 step 4
    const int wb  = (r & 7) << 4;          // 0..112 step 16

    const int tr = tid >> 4;               // co group
    const int tc = tid & 15;               // px group

    float acc[4][4];
#pragma unroll
    for (int j = 0; j < 4; ++j)
#pragma unroll
        for (int i = 0; i < 4; ++i) acc[j][i] = 0.f;

    for (int k = 0; k < K2_; ++k) {
        __syncthreads();

        // ---- phase 1: per-pixel bilinear params + W_k staging ----
        if (tid < 64) {
            const int px  = tid;
            const int ho  = hb + (px >> 4);
            const int wo  = wb + (px & 15);
            const int ki = k / 3, kj = k % 3;
            const float dy = offset[((n * (2 * K2_) + 2 * k)     * HO_ + ho) * WO_ + wo];
            const float dx = offset[((n * (2 * K2_) + 2 * k + 1) * HO_ + ho) * WO_ + wo];
            const float m  = mask  [((n * K2_       + k)         * HO_ + ho) * WO_ + wo];
            const float yy = (float)(ho - 1 + ki) + dy;
            const float xx = (float)(wo - 1 + kj) + dx;
            const float y0f = floorf(yy), x0f = floorf(xx);
            const int y0 = (int)y0f, x0 = (int)x0f;
            const int yv0 = (y0 >= 0)  && (y0 < H_);
            const int yv1 = (y0 >= -1) && (y0 < H_ - 1);
            const int xv0 = (x0 >= 0)  && (x0 < W_);
            const int xv1 = (x0 >= -1) && (x0 < W_ - 1);
            const int vm = (yv0 & xv0) | ((yv0 & xv1) << 1)
                         | ((yv1 & xv0) << 2) | ((yv1 & xv1) << 3);
            cpA[px] = make_float4(yy - y0f, xx - x0f, m, __int_as_float(vm));
            cpB[px] = (y0 * W_ + x0) * CIN;
            cy0[px] = y0;
            cx0[px] = x0;
        }
        if (USE_WS) {
            const float4* wk = (const float4*)(wt + k * CIN * COUT);
#pragma unroll
            for (int e = 0; e < 4; ++e) {
                int i4 = e * 256 + tid;
                ((float4*)W_lds)[i4] = wk[i4];
            }
        } else {
#pragma unroll
            for (int e = 0; e < 16; ++e) {
                int i  = e * 256 + tid;
                int ci = i >> 6, co = i & 63;
                W_lds[ci * 64 + co] = weight[(co * CIN + ci) * K2_ + k];
            }
        }
        __syncthreads();

        // ---- phase 2: sample S[ci][px] = bilinear(x)*mask ----
        if (USE_NHWC) {
            // Wave = 64 ci (lane) x 4 px; coords wave-uniform -> coalesced loads.
            const int lane = tid & 63;
            const int wv   = tid >> 6;
            const float* base = xt + (size_t)n * (H_ * W_ * CIN);
#pragma unroll
            for (int e = 0; e < 4; ++e) {
                const int g   = e * 4 + wv;     // px group 0..15
                const int px0 = g * 4;
                float sp[4];
#pragma unroll
                for (int j = 0; j < 4; ++j) {
                    const int px = px0 + j;
                    const float4 P = cpA[px];
                    const int vm = __float_as_int(P.w);
                    const long long ob = (long long)cpB[px] + lane;
                    float c00 = (vm & 1) ? base[ob]                  : 0.f;
                    float c01 = (vm & 2) ? base[ob + CIN]            : 0.f;
                    float c10 = (vm & 4) ? base[ob + W_ * CIN]       : 0.f;
                    float c11 = (vm & 8) ? base[ob + W_ * CIN + CIN] : 0.f;
                    const float fy = P.x, fx = P.y;
                    float v = (c00 * (1.f - fy) + c10 * fy) * (1.f - fx)
                            + (c01 * (1.f - fy) + c11 * fy) * fx;
                    sp[j] = v * P.z;
                }
                *(float4*)&S_lds[lane * SLD + px0] =
                    make_float4(sp[0], sp[1], sp[2], sp[3]);
            }
        } else {
#pragma unroll
            for (int e = 0; e < 16; ++e) {
                int i  = e * 256 + tid;
                int ci = i >> 6, px = i & 63;
                int   y0 = cy0[px], x0 = cx0[px];
                const float4 P = cpA[px];
                float fy = P.x, fx = P.y, m = P.z;
                const float* xc = x + (size_t)(n * CIN + ci) * (H_ * W_);
                bool yv0 = (y0 >= 0)  && (y0 < H_);
                bool yv1 = (y0 >= -1) && (y0 < H_ - 1);
                bool xv0 = (x0 >= 0)  && (x0 < W_);
                bool xv1 = (x0 >= -1) && (x0 < W_ - 1);
                float v00 = (yv0 && xv0) ? xc[y0 * W_ + x0]           : 0.f;
                float v01 = (yv0 && xv1) ? xc[y0 * W_ + x0 + 1]       : 0.f;
                float v10 = (yv1 && xv0) ? xc[(y0 + 1) * W_ + x0]     : 0.f;
                float v11 = (yv1 && xv1) ? xc[(y0 + 1) * W_ + x0 + 1] : 0.f;
                float v = (v00 * (1.f - fy) + v10 * fy) * (1.f - fx)
                        + (v01 * (1.f - fy) + v11 * fy) * fx;
                S_lds[ci * SLD + px] = v * m;
            }
        }
        __syncthreads();

        // ---- phase 3: 64x64x64 mini-GEMM, 4x4 per thread ----
#pragma unroll 8
        for (int ci = 0; ci < CIN; ++ci) {
            const float4 a = *(const float4*)&W_lds[ci * 64 + tr * 4];
            const float4 b = *(const float4*)&S_lds[ci * SLD + tc * 4];
            acc[0][0] += a.x * b.x; acc[0][1] += a.x * b.y;
            acc[0][2] += a.x * b.z; acc[0][3] += a.x * b.w;
            acc[1][0] += a.y * b.x; acc[1][1] += a.y * b.y;
            acc[1][2] += a.y * b.z; acc[1][3] += a.y * b.w;
            acc[2][0] += a.z * b.x; acc[2][1] += a.z * b.y;
            acc[2][2] += a.z * b.z; acc[2][3] += a.z * b.w;
            acc[3][0] += a.w * b.x; acc[3][1] += a.w * b.y;
            acc[3][2] += a.w * b.z; acc[3][3] += a.w * b.w;
        }
    }

    // ---- epilogue: coalesced float4 stores ----
    const int co0  = tr * 4;
    const int hoE  = hb + (tc >> 2);
    const int woE  = wb + (tc & 3) * 4;
#pragma unroll
    for (int j = 0; j < 4; ++j) {
        float4 v;
        v.x = acc[j][0]; v.y = acc[j][1]; v.z = acc[j][2]; v.w = acc[j][3];
        *(float4*)&out[((size_t)(n * COUT + co0 + j) * HO_ + hoE) * WO_ + woE] = v;
    }
}

extern "C" void kernel_launch(void* const* d_in, const int* in_sizes, int n_in,
                              void* d_out, int out_size, void* d_ws, size_t ws_size,
                              hipStream_t stream) {
    const float* x      = (const float*)d_in[0];
    const float* offset = (const float*)d_in[1];
    const float* mask   = (const float*)d_in[2];
    const float* weight = (const float*)d_in[3];
    float* out = (float*)d_out;

    const size_t wt_bytes = (size_t)K2_ * CIN * COUT * sizeof(float);      // 144 KB
    const size_t xt_bytes = (size_t)N_ * H_ * W_ * CIN * sizeof(float);    // 16 MB

    if (ws_size >= wt_bytes + xt_bytes) {
        float* wt = (float*)d_ws;
        float* xt = (float*)((char*)d_ws + wt_bytes);
        DeformConv2d_wtrans<<<(COUT * CIN * K2_ + 255) / 256, 256, 0, stream>>>(weight, wt);
        DeformConv2d_nhwc<<<4096, 256, 0, stream>>>(x, xt);
        DeformConv2d_kernel<true, true><<<1024, 256, 0, stream>>>(
            x, offset, mask, weight, wt, xt, out);
    } else if (ws_size >= wt_bytes) {
        float* wt = (float*)d_ws;
        DeformConv2d_wtrans<<<(COUT * CIN * K2_ + 255) / 256, 256, 0, stream>>>(weight, wt);
        DeformConv2d_kernel<true, false><<<1024, 256, 0, stream>>>(
            x, offset, mask, weight, wt, nullptr, out);
    } else {
        DeformConv2d_kernel<false, false><<<1024, 256, 0, stream>>>(
            x, offset, mask, weight, nullptr, nullptr, out);
    }
}

// Round 4
// 77.483 us; speedup vs baseline: 1.8873x; 1.4725x over previous
//
#include <hip/hip_runtime.h>

#define N_    4
#define CIN   64
#define COUT  64
#define H_    128
#define W_    128
#define HO_   128
#define WO_   128
#define K2_   9

typedef __attribute__((ext_vector_type(8))) short  short8;   // 8 bf16 (4 VGPRs)
typedef __attribute__((ext_vector_type(4))) float  f32x4;    // MFMA accumulator

__device__ __forceinline__ unsigned short f32_to_bf16_rne(float f) {
    unsigned int u = __float_as_uint(f);
    u += 0x7fffu + ((u >> 16) & 1u);
    return (unsigned short)(u >> 16);
}

// Pack weights into MFMA A-fragment order (bf16):
// wf[((k*4 + wv)*2 + kk)*512 + lane*8 + j] = W[co = 16*wv + (lane&15)]
//                                             [ci = 32*kk + (lane>>4)*8 + j] at tap k.
__global__ __launch_bounds__(256) void DeformConv2d_wfrag(
    const float* __restrict__ w, unsigned short* __restrict__ wf) {
    int i  = blockIdx.x * 256 + threadIdx.x;          // 0..36863
    int j  = i & 7;
    int l  = (i >> 3) & 63;
    int kk = (i >> 9) & 1;
    int wv = (i >> 10) & 3;
    int k  = i >> 12;
    int co = 16 * wv + (l & 15);
    int ci = 32 * kk + ((l >> 4) << 3) + j;
    wf[i] = f32_to_bf16_rne(w[(co * CIN + ci) * K2_ + k]);
}

// One-shot NCHW -> NHWC: xt[n][y][x][c] = x[n][c][y][x]. LDS-tiled.
__global__ __launch_bounds__(256) void DeformConv2d_nhwc(const float* __restrict__ x,
                                                         float* __restrict__ xt) {
    __shared__ float tile[64][17];
    const int b  = blockIdx.x;            // 4096 = n(4) * y(128) * xstrip(8)
    const int xs = (b & 7) << 4;
    const int y  = (b >> 3) & 127;
    const int n  = b >> 10;
    const int t  = threadIdx.x;
    const int xi = t & 15, c0 = t >> 4;
#pragma unroll
    for (int p = 0; p < 4; ++p) {
        int c = c0 + p * 16;
        tile[c][xi] = x[((size_t)(n * 64 + c) * 128 + y) * 128 + xs + xi];
    }
    __syncthreads();
    const int cw = t & 63, x4 = t >> 6;
#pragma unroll
    for (int q = 0; q < 4; ++q) {
        int xw = q * 4 + x4;
        xt[((size_t)((n * 128 + y) * 128) + xs + xw) * 64 + cw] = tile[cw][xw];
    }
}

// Main kernel: block = 64 c_out x (4 ho x 16 wo) pixels, 4 waves.
// Wave wv owns co rows [16wv, 16wv+16) x all 64 px = 4 tiles of 16x16.
__global__ __launch_bounds__(256, 4) void DeformConv2d_mfma(
    const float* __restrict__ offset,       // [N,2*K2,HO,WO]
    const float* __restrict__ mask,         // [N,K2,HO,WO]
    const unsigned short* __restrict__ wf,  // bf16 A-fragments
    const float* __restrict__ xt,           // [N,H,W,CIN]
    float* __restrict__ out)                // [N,COUT,HO,WO]
{
    // S_bf[px][ci] bf16, XOR-swizzled: element (px,ci) at px*64 + (ci ^ ((px&7)<<3)).
    __shared__ unsigned short S_bf[64 * 64];  // 8 KB
    __shared__ float4 cpA[64];                // {fy, fx, m, bitcast(validmask)}
    __shared__ int    cpB[64];                // (y0*W + x0)*CIN

    const int tid  = threadIdx.x;
    const int lane = tid & 63;
    const int wv   = tid >> 6;

    // Bijective XCD chunk swizzle (1024 % 8 == 0).
    const int raw = blockIdx.x;
    const int swz = (raw & 7) * 128 + (raw >> 3);
    const int n   = swz >> 8;
    const int r   = swz & 255;
    const int hb  = (r >> 3) << 2;         // 0..124 step 4
    const int wb  = (r & 7) << 4;          // 0..112 step 16

    f32x4 acc[4];
#pragma unroll
    for (int t = 0; t < 4; ++t) acc[t] = (f32x4){0.f, 0.f, 0.f, 0.f};

    const float* xbase = xt + (size_t)n * (H_ * W_ * CIN);
    const short8* wfp  = (const short8*)wf;

    for (int k = 0; k < K2_; ++k) {
        __syncthreads();   // prev tap's MFMA done reading S_bf / cpA

        // A-fragments for this tap (global, L1/L2-resident; latency hides under sampling)
        const int wbase = (k * 4 + wv) * 2 * 64;
        short8 afr0 = wfp[wbase + lane];        // kk=0: ci 0..31
        short8 afr1 = wfp[wbase + 64 + lane];   // kk=1: ci 32..63

        // ---- phase 1: per-pixel bilinear params (wave 0) ----
        if (tid < 64) {
            const int px = tid;
            const int ho = hb + (px >> 4);
            const int wo = wb + (px & 15);
            const int ki = k / 3, kj = k % 3;
            const float dy = offset[((n * (2 * K2_) + 2 * k)     * HO_ + ho) * WO_ + wo];
            const float dx = offset[((n * (2 * K2_) + 2 * k + 1) * HO_ + ho) * WO_ + wo];
            const float m  = mask  [((n * K2_       + k)         * HO_ + ho) * WO_ + wo];
            const float yy = (float)(ho - 1 + ki) + dy;
            const float xx = (float)(wo - 1 + kj) + dx;
            const float y0f = floorf(yy), x0f = floorf(xx);
            const int y0 = (int)y0f, x0 = (int)x0f;
            const int yv0 = (y0 >= 0)  && (y0 < H_);
            const int yv1 = (y0 >= -1) && (y0 < H_ - 1);
            const int xv0 = (x0 >= 0)  && (x0 < W_);
            const int xv1 = (x0 >= -1) && (x0 < W_ - 1);
            const int vm = (yv0 & xv0) | ((yv0 & xv1) << 1)
                         | ((yv1 & xv0) << 2) | ((yv1 & xv1) << 3);
            cpA[px] = make_float4(yy - y0f, xx - x0f, m, __int_as_float(vm));
            cpB[px] = (y0 * W_ + x0) * CIN;
        }
        __syncthreads();

        // ---- phase 2: sample -> bf16 S_bf[px][ci] (lane = ci, coords wave-uniform) ----
#pragma unroll
        for (int e = 0; e < 4; ++e) {
            const int px0 = (e * 4 + wv) * 4;
#pragma unroll
            for (int j = 0; j < 4; ++j) {
                const int px = px0 + j;
                const float4 P = cpA[px];
                const int vm = __float_as_int(P.w);
                const int ob = cpB[px] + lane;
                float c00 = (vm & 1) ? xbase[ob]                  : 0.f;
                float c01 = (vm & 2) ? xbase[ob + CIN]            : 0.f;
                float c10 = (vm & 4) ? xbase[ob + W_ * CIN]       : 0.f;
                float c11 = (vm & 8) ? xbase[ob + W_ * CIN + CIN] : 0.f;
                const float fy = P.x, fx = P.y;
                float v = (c00 * (1.f - fy) + c10 * fy) * (1.f - fx)
                        + (c01 * (1.f - fy) + c11 * fy) * fx;
                S_bf[px * 64 + (lane ^ ((px & 7) << 3))] = f32_to_bf16_rne(v * P.z);
            }
        }
        __syncthreads();

        // ---- phase 3: 8x mfma_f32_16x16x32_bf16 (4 px-tiles x 2 k-halves) ----
#pragma unroll
        for (int t = 0; t < 4; ++t) {
            const int px   = 16 * t + (lane & 15);
            const int rowb = px * 64;
            const int p8   = (px & 7) << 3;
            const int ci0  = (lane >> 4) << 3;
            const short8 b0 = *(const short8*)&S_bf[rowb + (ci0        ^ p8)];
            const short8 b1 = *(const short8*)&S_bf[rowb + ((32 + ci0) ^ p8)];
            acc[t] = __builtin_amdgcn_mfma_f32_16x16x32_bf16(afr0, b0, acc[t], 0, 0, 0);
            acc[t] = __builtin_amdgcn_mfma_f32_16x16x32_bf16(afr1, b1, acc[t], 0, 0, 0);
        }
    }

    // ---- epilogue: D[m][n] with col = lane&15 (px), row = (lane>>4)*4 + reg (co) ----
    const int co0 = 16 * wv + ((lane >> 4) << 2);
    const int woE = wb + (lane & 15);
#pragma unroll
    for (int t = 0; t < 4; ++t) {
        const int hoE = hb + t;
#pragma unroll
        for (int rr = 0; rr < 4; ++rr) {
            out[((size_t)(n * COUT + co0 + rr) * HO_ + hoE) * WO_ + woE] = acc[t][rr];
        }
    }
}

// fp32 fallback (no workspace needed beyond nothing): round-1 structure.
__global__ __launch_bounds__(256, 4) void DeformConv2d_fallback(
    const float* __restrict__ x, const float* __restrict__ offset,
    const float* __restrict__ mask, const float* __restrict__ weight,
    float* __restrict__ out)
{
    __shared__ float W_lds[CIN * COUT];
    __shared__ float S_lds[CIN * 68];
    __shared__ float cfy[64], cfx[64], cm[64];
    __shared__ int   cy0[64], cx0[64];

    const int tid = threadIdx.x;
    const int raw = blockIdx.x;
    const int swz = (raw & 7) * 128 + (raw >> 3);
    const int n   = swz >> 8;
    const int r   = swz & 255;
    const int hb  = (r >> 3) << 2;
    const int wb  = (r & 7) << 4;
    const int tr = tid >> 4, tc = tid & 15;

    float acc[4][4];
#pragma unroll
    for (int j = 0; j < 4; ++j)
#pragma unroll
        for (int i = 0; i < 4; ++i) acc[j][i] = 0.f;

    for (int k = 0; k < K2_; ++k) {
        __syncthreads();
        if (tid < 64) {
            const int px = tid, ho = hb + (px >> 4), wo = wb + (px & 15);
            const int ki = k / 3, kj = k % 3;
            const float dy = offset[((n * 18 + 2 * k)     * HO_ + ho) * WO_ + wo];
            const float dx = offset[((n * 18 + 2 * k + 1) * HO_ + ho) * WO_ + wo];
            const float m  = mask  [((n * 9  + k)         * HO_ + ho) * WO_ + wo];
            const float yy = (float)(ho - 1 + ki) + dy;
            const float xx = (float)(wo - 1 + kj) + dx;
            const float y0f = floorf(yy), x0f = floorf(xx);
            cy0[px] = (int)y0f; cx0[px] = (int)x0f;
            cfy[px] = yy - y0f; cfx[px] = xx - x0f; cm[px] = m;
        }
#pragma unroll
        for (int e = 0; e < 16; ++e) {
            int i = e * 256 + tid, ci = i >> 6, co = i & 63;
            W_lds[ci * 64 + co] = weight[(co * CIN + ci) * K2_ + k];
        }
        __syncthreads();
#pragma unroll
        for (int e = 0; e < 16; ++e) {
            int i = e * 256 + tid, ci = i >> 6, px = i & 63;
            int   y0 = cy0[px], x0 = cx0[px];
            float fy = cfy[px], fx = cfx[px], m = cm[px];
            const float* xc = x + (size_t)(n * CIN + ci) * (H_ * W_);
            bool yv0 = (y0 >= 0)  && (y0 < H_);
            bool yv1 = (y0 >= -1) && (y0 < H_ - 1);
            bool xv0 = (x0 >= 0)  && (x0 < W_);
            bool xv1 = (x0 >= -1) && (x0 < W_ - 1);
            float v00 = (yv0 && xv0) ? xc[y0 * W_ + x0]           : 0.f;
            float v01 = (yv0 && xv1) ? xc[y0 * W_ + x0 + 1]       : 0.f;
            float v10 = (yv1 && xv0) ? xc[(y0 + 1) * W_ + x0]     : 0.f;
            float v11 = (yv1 && xv1) ? xc[(y0 + 1) * W_ + x0 + 1] : 0.f;
            float v = (v00 * (1.f - fy) + v10 * fy) * (1.f - fx)
                    + (v01 * (1.f - fy) + v11 * fy) * fx;
            S_lds[ci * 68 + px] = v * m;
        }
        __syncthreads();
#pragma unroll 8
        for (int ci = 0; ci < CIN; ++ci) {
            const float4 a = *(const float4*)&W_lds[ci * 64 + tr * 4];
            const float4 b = *(const float4*)&S_lds[ci * 68 + tc * 4];
            acc[0][0] += a.x * b.x; acc[0][1] += a.x * b.y; acc[0][2] += a.x * b.z; acc[0][3] += a.x * b.w;
            acc[1][0] += a.y * b.x; acc[1][1] += a.y * b.y; acc[1][2] += a.y * b.z; acc[1][3] += a.y * b.w;
            acc[2][0] += a.z * b.x; acc[2][1] += a.z * b.y; acc[2][2] += a.z * b.z; acc[2][3] += a.z * b.w;
            acc[3][0] += a.w * b.x; acc[3][1] += a.w * b.y; acc[3][2] += a.w * b.z; acc[3][3] += a.w * b.w;
        }
    }
    const int co0 = tr * 4, hoE = hb + (tc >> 2), woE = wb + (tc & 3) * 4;
#pragma unroll
    for (int j = 0; j < 4; ++j) {
        float4 v; v.x = acc[j][0]; v.y = acc[j][1]; v.z = acc[j][2]; v.w = acc[j][3];
        *(float4*)&out[((size_t)(n * COUT + co0 + j) * HO_ + hoE) * WO_ + woE] = v;
    }
}

extern "C" void kernel_launch(void* const* d_in, const int* in_sizes, int n_in,
                              void* d_out, int out_size, void* d_ws, size_t ws_size,
                              hipStream_t stream) {
    const float* x      = (const float*)d_in[0];
    const float* offset = (const float*)d_in[1];
    const float* mask   = (const float*)d_in[2];
    const float* weight = (const float*)d_in[3];
    float* out = (float*)d_out;

    const size_t wf_bytes = (size_t)K2_ * 4 * 2 * 64 * 8 * sizeof(unsigned short); // 73728
    const size_t xt_bytes = (size_t)N_ * H_ * W_ * CIN * sizeof(float);            // 16 MB

    if (ws_size >= wf_bytes + xt_bytes) {
        unsigned short* wfb = (unsigned short*)d_ws;
        float* xt = (float*)((char*)d_ws + wf_bytes);
        DeformConv2d_wfrag<<<144, 256, 0, stream>>>(weight, wfb);
        DeformConv2d_nhwc<<<4096, 256, 0, stream>>>(x, xt);
        DeformConv2d_mfma<<<1024, 256, 0, stream>>>(offset, mask, wfb, xt, out);
    } else {
        DeformConv2d_fallback<<<1024, 256, 0, stream>>>(x, offset, mask, weight, out);
    }
}

// Round 6
// 56.377 us; speedup vs baseline: 2.5939x; 1.3744x over previous
//
#include <hip/hip_runtime.h>

#define N_    4
#define CIN   64
#define COUT  64
#define H_    128
#define W_    128
#define HO_   128
#define WO_   128
#define K2_   9

typedef __attribute__((ext_vector_type(8))) short  short8;   // 8 bf16 (4 VGPRs)
typedef __attribute__((ext_vector_type(4))) float  f32x4;    // MFMA accumulator

__device__ __forceinline__ unsigned short f32_to_bf16_rne(float f) {
    unsigned int u = __float_as_uint(f);
    u += 0x7fffu + ((u >> 16) & 1u);
    return (unsigned short)(u >> 16);
}
__device__ __forceinline__ unsigned int pk_bf16(float lo, float hi) {
    unsigned int r;
    asm("v_cvt_pk_bf16_f32 %0, %1, %2" : "=v"(r) : "v"(lo), "v"(hi));
    return r;
}
__device__ __forceinline__ float bflo(unsigned int u) { return __uint_as_float(u << 16); }
__device__ __forceinline__ float bfhi(unsigned int u) { return __uint_as_float(u & 0xffff0000u); }

// bilinear combine of one packed pair (2 ci) across 4 corners -> packed bf16
__device__ __forceinline__ unsigned int comb1(
    unsigned int a00, unsigned int a01, unsigned int a10, unsigned int a11,
    float w00, float w01, float w10, float w11) {
    float lo = w00 * bflo(a00) + w01 * bflo(a01) + w10 * bflo(a10) + w11 * bflo(a11);
    float hi = w00 * bfhi(a00) + w01 * bfhi(a01) + w10 * bfhi(a10) + w11 * bfhi(a11);
    return pk_bf16(lo, hi);
}

// Pack weights into MFMA A-fragment order (bf16):
// wf[((k*4 + t)*2 + kk)*512 + lane*8 + j] = W[co = 16t + (lane&15)]
//                                            [ci = 32kk + (lane>>4)*8 + j] at tap k.
__global__ __launch_bounds__(256) void DeformConv2d_wfrag(
    const float* __restrict__ w, unsigned short* __restrict__ wf) {
    int i  = blockIdx.x * 256 + threadIdx.x;          // 0..36863
    int j  = i & 7;
    int l  = (i >> 3) & 63;
    int kk = (i >> 9) & 1;
    int t  = (i >> 10) & 3;
    int k  = i >> 12;
    int co = 16 * t + (l & 15);
    int ci = 32 * kk + ((l >> 4) << 3) + j;
    wf[i] = f32_to_bf16_rne(w[(co * CIN + ci) * K2_ + k]);
}

// One-shot NCHW f32 -> NHWC bf16: xtb[n][y][x][c].
__global__ __launch_bounds__(256) void DeformConv2d_nhwc_bf16(
    const float* __restrict__ x, unsigned short* __restrict__ xtb) {
    __shared__ float tile[64][17];
    const int b  = blockIdx.x;            // 4096 = n(4) * y(128) * xstrip(8)
    const int xs = (b & 7) << 4;
    const int y  = (b >> 3) & 127;
    const int n  = b >> 10;
    const int t  = threadIdx.x;
    const int xi = t & 15, c0 = t >> 4;
#pragma unroll
    for (int p = 0; p < 4; ++p) {
        int c = c0 + p * 16;
        tile[c][xi] = x[((size_t)(n * 64 + c) * 128 + y) * 128 + xs + xi];
    }
    __syncthreads();
    unsigned int* xq = (unsigned int*)xtb;
    const int cw2 = t & 31, x4 = t >> 5;   // x4: 0..7
#pragma unroll
    for (int q = 0; q < 2; ++q) {
        int xw = q * 8 + x4;
        unsigned int pk = pk_bf16(tile[2 * cw2][xw], tile[2 * cw2 + 1][xw]);
        xq[((size_t)((n * 128 + y) * 128) + xs + xw) * 32 + cw2] = pk;
    }
}

// Main kernel: block = 4 waves; wave wv owns (ho = hb+wv) x 16 wo x all 64 co.
// Barrier-light: 1 barrier/tap (A-fragment LDS double-buffer only). S stays in
// registers: each lane samples its px's ci slice directly into the B-fragment.
__global__ __launch_bounds__(256, 4) void DeformConv2d_mfma(
    const float* __restrict__ offset,       // [N,2*K2,HO,WO]
    const float* __restrict__ mask,         // [N,K2,HO,WO]
    const unsigned short* __restrict__ wf,  // bf16 A-fragments [9][512] short8
    const unsigned short* __restrict__ xtb, // bf16 NHWC [N,H,W,CIN]
    float* __restrict__ out)                // [N,COUT,HO,WO] f32
{
    __shared__ short8 Afrag[2][512];        // 2 x 8 KB double buffer

    const int tid  = threadIdx.x;
    const int lane = tid & 63;
    const int wv   = tid >> 6;
    const int g    = lane >> 4;             // ci group
    const int pxw  = lane & 15;             // px within wave = wo offset
    const int ci0  = g * 8;

    // Bijective XCD chunk swizzle (1024 % 8 == 0).
    const int raw = blockIdx.x;
    const int swz = (raw & 7) * 128 + (raw >> 3);
    const int n   = swz >> 8;
    const int r   = swz & 255;
    const int hb  = (r >> 3) << 2;          // 0..124 step 4
    const int wb  = (r & 7) << 4;           // 0..112 step 16
    const int ho  = hb + wv;
    const int wo  = wb + pxw;

    const unsigned short* xb = xtb + (size_t)n * (H_ * W_ * CIN);
    const short8* wfq = (const short8*)wf;  // [9][512]

    f32x4 acc[4];
#pragma unroll
    for (int t = 0; t < 4; ++t) acc[t] = (f32x4){0.f, 0.f, 0.f, 0.f};

    // prologue: stage tap 0 A-fragments
    Afrag[0][tid]       = wfq[tid];
    Afrag[0][256 + tid] = wfq[256 + tid];
    __syncthreads();

#pragma unroll
    for (int k = 0; k < K2_; ++k) {
        const int KI = k / 3, KJ = k % 3;

        // issue next tap's A-stage loads early (write-late after MFMA)
        short8 s0, s1;
        if (k < 8) {
            s0 = wfq[(k + 1) * 512 + tid];
            s1 = wfq[(k + 1) * 512 + 256 + tid];
        }

        // per-lane params (redundant across ci groups; 1-line broadcast loads)
        const float dy = offset[((n * 18 + 2 * k)     * HO_ + ho) * WO_ + wo];
        const float dx = offset[((n * 18 + 2 * k + 1) * HO_ + ho) * WO_ + wo];
        const float m  = mask  [((n * 9  + k)         * HO_ + ho) * WO_ + wo];
        const float yy = (float)(ho - 1 + KI) + dy;
        const float xx = (float)(wo - 1 + KJ) + dx;
        const float y0f = floorf(yy), x0f = floorf(xx);
        const int   y0  = (int)y0f,  x0  = (int)x0f;
        const float fy  = yy - y0f,  fx  = xx - x0f;

        const bool yv0 = (y0 >= 0)  && (y0 < H_);
        const bool yv1 = (y0 >= -1) && (y0 < H_ - 1);
        const bool xv0 = (x0 >= 0)  && (x0 < W_);
        const bool xv1 = (x0 >= -1) && (x0 < W_ - 1);
        const float gy0 = (1.f - fy) * m, gy1 = fy * m;
        const float w00 = (yv0 && xv0) ? gy0 * (1.f - fx) : 0.f;
        const float w01 = (yv0 && xv1) ? gy0 * fx         : 0.f;
        const float w10 = (yv1 && xv0) ? gy1 * (1.f - fx) : 0.f;
        const float w11 = (yv1 && xv1) ? gy1 * fx         : 0.f;

        // clamped corner bases (matches reference clip; weights zero invalid)
        const int y0c = min(max(y0, 0), H_ - 1), y1c = min(max(y0 + 1, 0), H_ - 1);
        const int x0c = min(max(x0, 0), W_ - 1), x1c = min(max(x0 + 1, 0), W_ - 1);
        const uint4* p00 = (const uint4*)(xb + (y0c * W_ + x0c) * CIN + ci0);
        const uint4* p01 = (const uint4*)(xb + (y0c * W_ + x1c) * CIN + ci0);
        const uint4* p10 = (const uint4*)(xb + (y1c * W_ + x0c) * CIN + ci0);
        const uint4* p11 = (const uint4*)(xb + (y1c * W_ + x1c) * CIN + ci0);
        // uint4 = 8 shorts; ci+32 is 4 uint4s ahead (p[2] was the round-5 bug: ci+16)
        const uint4 c00a = p00[0], c00b = p00[4];   // b-halves: ci0, ci0+32
        const uint4 c01a = p01[0], c01b = p01[4];
        const uint4 c10a = p10[0], c10b = p10[4];
        const uint4 c11a = p11[0], c11b = p11[4];

        // combine -> B fragments (bf16), S never touches LDS
        union F8 { unsigned int u[4]; short8 s; } f0, f1;
        f0.u[0] = comb1(c00a.x, c01a.x, c10a.x, c11a.x, w00, w01, w10, w11);
        f0.u[1] = comb1(c00a.y, c01a.y, c10a.y, c11a.y, w00, w01, w10, w11);
        f0.u[2] = comb1(c00a.z, c01a.z, c10a.z, c11a.z, w00, w01, w10, w11);
        f0.u[3] = comb1(c00a.w, c01a.w, c10a.w, c11a.w, w00, w01, w10, w11);
        f1.u[0] = comb1(c00b.x, c01b.x, c10b.x, c11b.x, w00, w01, w10, w11);
        f1.u[1] = comb1(c00b.y, c01b.y, c10b.y, c11b.y, w00, w01, w10, w11);
        f1.u[2] = comb1(c00b.z, c01b.z, c10b.z, c11b.z, w00, w01, w10, w11);
        f1.u[3] = comb1(c00b.w, c01b.w, c10b.w, c11b.w, w00, w01, w10, w11);

        // MFMA: 4 co-tiles x 2 k-halves
#pragma unroll
        for (int t = 0; t < 4; ++t) {
            const short8 A0 = Afrag[k & 1][(t * 2 + 0) * 64 + lane];
            const short8 A1 = Afrag[k & 1][(t * 2 + 1) * 64 + lane];
            acc[t] = __builtin_amdgcn_mfma_f32_16x16x32_bf16(A0, f0.s, acc[t], 0, 0, 0);
            acc[t] = __builtin_amdgcn_mfma_f32_16x16x32_bf16(A1, f1.s, acc[t], 0, 0, 0);
        }

        // write-late A-stage + single barrier per tap
        if (k < 8) {
            Afrag[(k + 1) & 1][tid]       = s0;
            Afrag[(k + 1) & 1][256 + tid] = s1;
            __syncthreads();
        }
    }

    // epilogue: D col = lane&15 (px/wo), row = g*4 + reg (co within tile t)
#pragma unroll
    for (int t = 0; t < 4; ++t) {
#pragma unroll
        for (int rr = 0; rr < 4; ++rr) {
            out[((size_t)(n * COUT + 16 * t + g * 4 + rr) * HO_ + ho) * WO_ + wo] = acc[t][rr];
        }
    }
}

// fp32 fallback (no workspace): known-correct round-1 structure.
__global__ __launch_bounds__(256, 4) void DeformConv2d_fallback(
    const float* __restrict__ x, const float* __restrict__ offset,
    const float* __restrict__ mask, const float* __restrict__ weight,
    float* __restrict__ out)
{
    __shared__ float W_lds[CIN * COUT];
    __shared__ float S_lds[CIN * 68];
    __shared__ float cfy[64], cfx[64], cm[64];
    __shared__ int   cy0[64], cx0[64];

    const int tid = threadIdx.x;
    const int raw = blockIdx.x;
    const int swz = (raw & 7) * 128 + (raw >> 3);
    const int n   = swz >> 8;
    const int r   = swz & 255;
    const int hb  = (r >> 3) << 2;
    const int wb  = (r & 7) << 4;
    const int tr = tid >> 4, tc = tid & 15;

    float acc[4][4];
#pragma unroll
    for (int j = 0; j < 4; ++j)
#pragma unroll
        for (int i = 0; i < 4; ++i) acc[j][i] = 0.f;

    for (int k = 0; k < K2_; ++k) {
        __syncthreads();
        if (tid < 64) {
            const int px = tid, ho = hb + (px >> 4), wo = wb + (px & 15);
            const int ki = k / 3, kj = k % 3;
            const float dy = offset[((n * 18 + 2 * k)     * HO_ + ho) * WO_ + wo];
            const float dx = offset[((n * 18 + 2 * k + 1) * HO_ + ho) * WO_ + wo];
            const float m  = mask  [((n * 9  + k)         * HO_ + ho) * WO_ + wo];
            const float yy = (float)(ho - 1 + ki) + dy;
            const float xx = (float)(wo - 1 + kj) + dx;
            const float y0f = floorf(yy), x0f = floorf(xx);
            cy0[px] = (int)y0f; cx0[px] = (int)x0f;
            cfy[px] = yy - y0f; cfx[px] = xx - x0f; cm[px] = m;
        }
#pragma unroll
        for (int e = 0; e < 16; ++e) {
            int i = e * 256 + tid, ci = i >> 6, co = i & 63;
            W_lds[ci * 64 + co] = weight[(co * CIN + ci) * K2_ + k];
        }
        __syncthreads();
#pragma unroll
        for (int e = 0; e < 16; ++e) {
            int i = e * 256 + tid, ci = i >> 6, px = i & 63;
            int   y0 = cy0[px], x0 = cx0[px];
            float fy = cfy[px], fx = cfx[px], m = cm[px];
            const float* xc = x + (size_t)(n * CIN + ci) * (H_ * W_);
            bool yv0 = (y0 >= 0)  && (y0 < H_);
            bool yv1 = (y0 >= -1) && (y0 < H_ - 1);
            bool xv0 = (x0 >= 0)  && (x0 < W_);
            bool xv1 = (x0 >= -1) && (x0 < W_ - 1);
            float v00 = (yv0 && xv0) ? xc[y0 * W_ + x0]           : 0.f;
            float v01 = (yv0 && xv1) ? xc[y0 * W_ + x0 + 1]       : 0.f;
            float v10 = (yv1 && xv0) ? xc[(y0 + 1) * W_ + x0]     : 0.f;
            float v11 = (yv1 && xv1) ? xc[(y0 + 1) * W_ + x0 + 1] : 0.f;
            float v = (v00 * (1.f - fy) + v10 * fy) * (1.f - fx)
                    + (v01 * (1.f - fy) + v11 * fy) * fx;
            S_lds[ci * 68 + px] = v * m;
        }
        __syncthreads();
#pragma unroll 8
        for (int ci = 0; ci < CIN; ++ci) {
            const float4 a = *(const float4*)&W_lds[ci * 64 + tr * 4];
            const float4 b = *(const float4*)&S_lds[ci * 68 + tc * 4];
            acc[0][0] += a.x * b.x; acc[0][1] += a.x * b.y; acc[0][2] += a.x * b.z; acc[0][3] += a.x * b.w;
            acc[1][0] += a.y * b.x; acc[1][1] += a.y * b.y; acc[1][2] += a.y * b.z; acc[1][3] += a.y * b.w;
            acc[2][0] += a.z * b.x; acc[2][1] += a.z * b.y; acc[2][2] += a.z * b.z; acc[2][3] += a.z * b.w;
            acc[3][0] += a.w * b.x; acc[3][1] += a.w * b.y; acc[3][2] += a.w * b.z; acc[3][3] += a.w * b.w;
        }
    }
    const int co0 = tr * 4, hoE = hb + (tc >> 2), woE = wb + (tc & 3) * 4;
#pragma unroll
    for (int j = 0; j < 4; ++j) {
        float4 v; v.x = acc[j][0]; v.y = acc[j][1]; v.z = acc[j][2]; v.w = acc[j][3];
        *(float4*)&out[((size_t)(n * COUT + co0 + j) * HO_ + hoE) * WO_ + woE] = v;
    }
}

extern "C" void kernel_launch(void* const* d_in, const int* in_sizes, int n_in,
                              void* d_out, int out_size, void* d_ws, size_t ws_size,
                              hipStream_t stream) {
    const float* x      = (const float*)d_in[0];
    const float* offset = (const float*)d_in[1];
    const float* mask   = (const float*)d_in[2];
    const float* weight = (const float*)d_in[3];
    float* out = (float*)d_out;

    const size_t wf_bytes = (size_t)K2_ * 8 * 64 * 8 * sizeof(unsigned short);        // 73728
    const size_t xt_bytes = (size_t)N_ * H_ * W_ * CIN * sizeof(unsigned short);      // 8 MB

    if (ws_size >= wf_bytes + xt_bytes) {
        unsigned short* wfb = (unsigned short*)d_ws;
        unsigned short* xtb = (unsigned short*)((char*)d_ws + wf_bytes);
        DeformConv2d_wfrag<<<144, 256, 0, stream>>>(weight, wfb);
        DeformConv2d_nhwc_bf16<<<4096, 256, 0, stream>>>(x, xtb);
        DeformConv2d_mfma<<<1024, 256, 0, stream>>>(offset, mask, wfb, xtb, out);
    } else {
        DeformConv2d_fallback<<<1024, 256, 0, stream>>>(x, offset, mask, weight, out);
    }
}

// Round 7
// 54.933 us; speedup vs baseline: 2.6621x; 1.0263x over previous
//
#include <hip/hip_runtime.h>

#define N_    4
#define CIN   64
#define COUT  64
#define H_    128
#define W_    128
#define HO_   128
#define WO_   128
#define K2_   9

typedef __attribute__((ext_vector_type(8))) short  short8;   // 8 bf16 (4 VGPRs)
typedef __attribute__((ext_vector_type(4))) float  f32x4;    // MFMA accumulator

__device__ __forceinline__ unsigned short f32_to_bf16_rne(float f) {
    unsigned int u = __float_as_uint(f);
    u += 0x7fffu + ((u >> 16) & 1u);
    return (unsigned short)(u >> 16);
}
__device__ __forceinline__ unsigned int pk_bf16(float lo, float hi) {
    unsigned int r;
    asm("v_cvt_pk_bf16_f32 %0, %1, %2" : "=v"(r) : "v"(lo), "v"(hi));
    return r;
}
__device__ __forceinline__ float bflo(unsigned int u) { return __uint_as_float(u << 16); }
__device__ __forceinline__ float bfhi(unsigned int u) { return __uint_as_float(u & 0xffff0000u); }

// bilinear combine of one packed pair (2 ci) across 4 corners -> packed bf16
__device__ __forceinline__ unsigned int comb1(
    unsigned int a00, unsigned int a01, unsigned int a10, unsigned int a11,
    float w00, float w01, float w10, float w11) {
    float lo = w00 * bflo(a00) + w01 * bflo(a01) + w10 * bflo(a10) + w11 * bflo(a11);
    float hi = w00 * bfhi(a00) + w01 * bfhi(a01) + w10 * bfhi(a10) + w11 * bfhi(a11);
    return pk_bf16(lo, hi);
}

// Pack weights into MFMA A-fragment order (bf16):
// wf[((k*4 + t)*2 + kk)*512 + lane*8 + j] = W[co = 16t + (lane&15)]
//                                            [ci = 32kk + (lane>>4)*8 + j] at tap k.
__global__ __launch_bounds__(256) void DeformConv2d_wfrag(
    const float* __restrict__ w, unsigned short* __restrict__ wf) {
    int i  = blockIdx.x * 256 + threadIdx.x;          // 0..36863
    int j  = i & 7;
    int l  = (i >> 3) & 63;
    int kk = (i >> 9) & 1;
    int t  = (i >> 10) & 3;
    int k  = i >> 12;
    int co = 16 * t + (l & 15);
    int ci = 32 * kk + ((l >> 4) << 3) + j;
    wf[i] = f32_to_bf16_rne(w[(co * CIN + ci) * K2_ + k]);
}

// One-shot NCHW f32 -> NHWC bf16: xtb[n][y][x][c].
__global__ __launch_bounds__(256) void DeformConv2d_nhwc_bf16(
    const float* __restrict__ x, unsigned short* __restrict__ xtb) {
    __shared__ float tile[64][17];
    const int b  = blockIdx.x;            // 4096 = n(4) * y(128) * xstrip(8)
    const int xs = (b & 7) << 4;
    const int y  = (b >> 3) & 127;
    const int n  = b >> 10;
    const int t  = threadIdx.x;
    const int xi = t & 15, c0 = t >> 4;
#pragma unroll
    for (int p = 0; p < 4; ++p) {
        int c = c0 + p * 16;
        tile[c][xi] = x[((size_t)(n * 64 + c) * 128 + y) * 128 + xs + xi];
    }
    __syncthreads();
    unsigned int* xq = (unsigned int*)xtb;
    const int cw2 = t & 31, x4 = t >> 5;   // x4: 0..7
#pragma unroll
    for (int q = 0; q < 2; ++q) {
        int xw = q * 8 + x4;
        unsigned int pk = pk_bf16(tile[2 * cw2][xw], tile[2 * cw2 + 1][xw]);
        xq[((size_t)((n * 128 + y) * 128) + xs + xw) * 32 + cw2] = pk;
    }
}

// Main kernel: block = 4 waves; wave wv owns (ho = hb+wv) x 16 wo x all 64 co.
// Round 7: param preload (27 regs) + 1-deep corner-load software pipeline.
__global__ __launch_bounds__(256, 4) void DeformConv2d_mfma(
    const float* __restrict__ offset,       // [N,2*K2,HO,WO]
    const float* __restrict__ mask,         // [N,K2,HO,WO]
    const unsigned short* __restrict__ wf,  // bf16 A-fragments [9][512] short8
    const unsigned short* __restrict__ xtb, // bf16 NHWC [N,H,W,CIN]
    float* __restrict__ out)                // [N,COUT,HO,WO] f32
{
    __shared__ short8 Afrag[2][512];        // 2 x 8 KB double buffer

    const int tid  = threadIdx.x;
    const int lane = tid & 63;
    const int wv   = tid >> 6;
    const int g    = lane >> 4;             // ci group
    const int pxw  = lane & 15;             // px within wave = wo offset
    const int ci0  = g * 8;

    // Bijective XCD chunk swizzle (1024 % 8 == 0).
    const int raw = blockIdx.x;
    const int swz = (raw & 7) * 128 + (raw >> 3);
    const int n   = swz >> 8;
    const int r   = swz & 255;
    const int hb  = (r >> 3) << 2;          // 0..124 step 4
    const int wb  = (r & 7) << 4;           // 0..112 step 16
    const int ho  = hb + wv;
    const int wo  = wb + pxw;

    const unsigned short* xb = xtb + (size_t)n * (H_ * W_ * CIN);
    const short8* wfq = (const short8*)wf;  // [9][512]

    f32x4 acc[4];
#pragma unroll
    for (int t = 0; t < 4; ++t) acc[t] = (f32x4){0.f, 0.f, 0.f, 0.f};

    // ---- preload ALL taps' params (27 independent loads, one wait) ----
    float dyv[K2_], dxv[K2_], mv[K2_];
#pragma unroll
    for (int k = 0; k < K2_; ++k) {
        dyv[k] = offset[((n * 18 + 2 * k)     * HO_ + ho) * WO_ + wo];
        dxv[k] = offset[((n * 18 + 2 * k + 1) * HO_ + ho) * WO_ + wo];
        mv[k]  = mask  [((n * 9  + k)         * HO_ + ho) * WO_ + wo];
    }

    // corner-load pipeline state (all indices constant-folded by full unroll)
    uint4 ca[2][8];       // [buf][c00a,c01a,c10a,c11a | c00b,c01b,c10b,c11b]
    float cw[2][4];

    auto issue = [&](int k, int b) {
        const int KI = k / 3, KJ = k % 3;
        const float yy  = (float)(ho - 1 + KI) + dyv[k];
        const float xx  = (float)(wo - 1 + KJ) + dxv[k];
        const float y0f = floorf(yy), x0f = floorf(xx);
        const int   y0  = (int)y0f,  x0  = (int)x0f;
        const float fy  = yy - y0f,  fx  = xx - x0f;
        const bool yv0 = (y0 >= 0)  && (y0 < H_);
        const bool yv1 = (y0 >= -1) && (y0 < H_ - 1);
        const bool xv0 = (x0 >= 0)  && (x0 < W_);
        const bool xv1 = (x0 >= -1) && (x0 < W_ - 1);
        const float m   = mv[k];
        const float gy0 = (1.f - fy) * m, gy1 = fy * m;
        cw[b][0] = (yv0 && xv0) ? gy0 * (1.f - fx) : 0.f;
        cw[b][1] = (yv0 && xv1) ? gy0 * fx         : 0.f;
        cw[b][2] = (yv1 && xv0) ? gy1 * (1.f - fx) : 0.f;
        cw[b][3] = (yv1 && xv1) ? gy1 * fx         : 0.f;
        const int y0c = min(max(y0, 0), H_ - 1), y1c = min(max(y0 + 1, 0), H_ - 1);
        const int x0c = min(max(x0, 0), W_ - 1), x1c = min(max(x0 + 1, 0), W_ - 1);
        const uint4* p00 = (const uint4*)(xb + (y0c * W_ + x0c) * CIN + ci0);
        const uint4* p01 = (const uint4*)(xb + (y0c * W_ + x1c) * CIN + ci0);
        const uint4* p10 = (const uint4*)(xb + (y1c * W_ + x0c) * CIN + ci0);
        const uint4* p11 = (const uint4*)(xb + (y1c * W_ + x1c) * CIN + ci0);
        ca[b][0] = p00[0]; ca[b][1] = p01[0]; ca[b][2] = p10[0]; ca[b][3] = p11[0];
        ca[b][4] = p00[4]; ca[b][5] = p01[4]; ca[b][6] = p10[4]; ca[b][7] = p11[4];
    };

    // prologue: stage tap 0 A-fragments + issue tap 0 corner loads
    Afrag[0][tid]       = wfq[tid];
    Afrag[0][256 + tid] = wfq[256 + tid];
    issue(0, 0);
    __syncthreads();

#pragma unroll
    for (int k = 0; k < K2_; ++k) {
        // prefetch next tap: A-frag global loads + corner loads into alt buffer
        short8 s0, s1;
        if (k < 8) {
            s0 = wfq[(k + 1) * 512 + tid];
            s1 = wfq[(k + 1) * 512 + 256 + tid];
            issue(k + 1, (k + 1) & 1);
        }

        // combine current buffer -> B fragments (bf16)
        const int b = k & 1;
        const float w00 = cw[b][0], w01 = cw[b][1], w10 = cw[b][2], w11 = cw[b][3];
        union F8 { unsigned int u[4]; short8 s; } f0, f1;
        f0.u[0] = comb1(ca[b][0].x, ca[b][1].x, ca[b][2].x, ca[b][3].x, w00, w01, w10, w11);
        f0.u[1] = comb1(ca[b][0].y, ca[b][1].y, ca[b][2].y, ca[b][3].y, w00, w01, w10, w11);
        f0.u[2] = comb1(ca[b][0].z, ca[b][1].z, ca[b][2].z, ca[b][3].z, w00, w01, w10, w11);
        f0.u[3] = comb1(ca[b][0].w, ca[b][1].w, ca[b][2].w, ca[b][3].w, w00, w01, w10, w11);
        f1.u[0] = comb1(ca[b][4].x, ca[b][5].x, ca[b][6].x, ca[b][7].x, w00, w01, w10, w11);
        f1.u[1] = comb1(ca[b][4].y, ca[b][5].y, ca[b][6].y, ca[b][7].y, w00, w01, w10, w11);
        f1.u[2] = comb1(ca[b][4].z, ca[b][5].z, ca[b][6].z, ca[b][7].z, w00, w01, w10, w11);
        f1.u[3] = comb1(ca[b][4].w, ca[b][5].w, ca[b][6].w, ca[b][7].w, w00, w01, w10, w11);

        // MFMA: 4 co-tiles x 2 k-halves
#pragma unroll
        for (int t = 0; t < 4; ++t) {
            const short8 A0 = Afrag[k & 1][(t * 2 + 0) * 64 + lane];
            const short8 A1 = Afrag[k & 1][(t * 2 + 1) * 64 + lane];
            acc[t] = __builtin_amdgcn_mfma_f32_16x16x32_bf16(A0, f0.s, acc[t], 0, 0, 0);
            acc[t] = __builtin_amdgcn_mfma_f32_16x16x32_bf16(A1, f1.s, acc[t], 0, 0, 0);
        }

        // write-late A-stage + single barrier per tap
        if (k < 8) {
            Afrag[(k + 1) & 1][tid]       = s0;
            Afrag[(k + 1) & 1][256 + tid] = s1;
            __syncthreads();
        }
    }

    // epilogue: D col = lane&15 (px/wo), row = g*4 + reg (co within tile t)
#pragma unroll
    for (int t = 0; t < 4; ++t) {
#pragma unroll
        for (int rr = 0; rr < 4; ++rr) {
            out[((size_t)(n * COUT + 16 * t + g * 4 + rr) * HO_ + ho) * WO_ + wo] = acc[t][rr];
        }
    }
}

// fp32 fallback (no workspace): known-correct round-1 structure.
__global__ __launch_bounds__(256, 4) void DeformConv2d_fallback(
    const float* __restrict__ x, const float* __restrict__ offset,
    const float* __restrict__ mask, const float* __restrict__ weight,
    float* __restrict__ out)
{
    __shared__ float W_lds[CIN * COUT];
    __shared__ float S_lds[CIN * 68];
    __shared__ float cfy[64], cfx[64], cm[64];
    __shared__ int   cy0[64], cx0[64];

    const int tid = threadIdx.x;
    const int raw = blockIdx.x;
    const int swz = (raw & 7) * 128 + (raw >> 3);
    const int n   = swz >> 8;
    const int r   = swz & 255;
    const int hb  = (r >> 3) << 2;
    const int wb  = (r & 7) << 4;
    const int tr = tid >> 4, tc = tid & 15;

    float acc[4][4];
#pragma unroll
    for (int j = 0; j < 4; ++j)
#pragma unroll
        for (int i = 0; i < 4; ++i) acc[j][i] = 0.f;

    for (int k = 0; k < K2_; ++k) {
        __syncthreads();
        if (tid < 64) {
            const int px = tid, ho = hb + (px >> 4), wo = wb + (px & 15);
            const int ki = k / 3, kj = k % 3;
            const float dy = offset[((n * 18 + 2 * k)     * HO_ + ho) * WO_ + wo];
            const float dx = offset[((n * 18 + 2 * k + 1) * HO_ + ho) * WO_ + wo];
            const float m  = mask  [((n * 9  + k)         * HO_ + ho) * WO_ + wo];
            const float yy = (float)(ho - 1 + ki) + dy;
            const float xx = (float)(wo - 1 + kj) + dx;
            const float y0f = floorf(yy), x0f = floorf(xx);
            cy0[px] = (int)y0f; cx0[px] = (int)x0f;
            cfy[px] = yy - y0f; cfx[px] = xx - x0f; cm[px] = m;
        }
#pragma unroll
        for (int e = 0; e < 16; ++e) {
            int i = e * 256 + tid, ci = i >> 6, co = i & 63;
            W_lds[ci * 64 + co] = weight[(co * CIN + ci) * K2_ + k];
        }
        __syncthreads();
#pragma unroll
        for (int e = 0; e < 16; ++e) {
            int i = e * 256 + tid, ci = i >> 6, px = i & 63;
            int   y0 = cy0[px], x0 = cx0[px];
            float fy = cfy[px], fx = cfx[px], m = cm[px];
            const float* xc = x + (size_t)(n * CIN + ci) * (H_ * W_);
            bool yv0 = (y0 >= 0)  && (y0 < H_);
            bool yv1 = (y0 >= -1) && (y0 < H_ - 1);
            bool xv0 = (x0 >= 0)  && (x0 < W_);
            bool xv1 = (x0 >= -1) && (x0 < W_ - 1);
            float v00 = (yv0 && xv0) ? xc[y0 * W_ + x0]           : 0.f;
            float v01 = (yv0 && xv1) ? xc[y0 * W_ + x0 + 1]       : 0.f;
            float v10 = (yv1 && xv0) ? xc[(y0 + 1) * W_ + x0]     : 0.f;
            float v11 = (yv1 && xv1) ? xc[(y0 + 1) * W_ + x0 + 1] : 0.f;
            float v = (v00 * (1.f - fy) + v10 * fy) * (1.f - fx)
                    + (v01 * (1.f - fy) + v11 * fy) * fx;
            S_lds[ci * 68 + px] = v * m;
        }
        __syncthreads();
#pragma unroll 8
        for (int ci = 0; ci < CIN; ++ci) {
            const float4 a = *(const float4*)&W_lds[ci * 64 + tr * 4];
            const float4 b = *(const float4*)&S_lds[ci * 68 + tc * 4];
            acc[0][0] += a.x * b.x; acc[0][1] += a.x * b.y; acc[0][2] += a.x * b.z; acc[0][3] += a.x * b.w;
            acc[1][0] += a.y * b.x; acc[1][1] += a.y * b.y; acc[1][2] += a.y * b.z; acc[1][3] += a.y * b.w;
            acc[2][0] += a.z * b.x; acc[2][1] += a.z * b.y; acc[2][2] += a.z * b.z; acc[2][3] += a.z * b.w;
            acc[3][0] += a.w * b.x; acc[3][1] += a.w * b.y; acc[3][2] += a.w * b.z; acc[3][3] += a.w * b.w;
        }
    }
    const int co0 = tr * 4, hoE = hb + (tc >> 2), woE = wb + (tc & 3) * 4;
#pragma unroll
    for (int j = 0; j < 4; ++j) {
        float4 v; v.x = acc[j][0]; v.y = acc[j][1]; v.z = acc[j][2]; v.w = acc[j][3];
        *(float4*)&out[((size_t)(n * COUT + co0 + j) * HO_ + hoE) * WO_ + woE] = v;
    }
}

extern "C" void kernel_launch(void* const* d_in, const int* in_sizes, int n_in,
                              void* d_out, int out_size, void* d_ws, size_t ws_size,
                              hipStream_t stream) {
    const float* x      = (const float*)d_in[0];
    const float* offset = (const float*)d_in[1];
    const float* mask   = (const float*)d_in[2];
    const float* weight = (const float*)d_in[3];
    float* out = (float*)d_out;

    const size_t wf_bytes = (size_t)K2_ * 8 * 64 * 8 * sizeof(unsigned short);        // 73728
    const size_t xt_bytes = (size_t)N_ * H_ * W_ * CIN * sizeof(unsigned short);      // 8 MB

    if (ws_size >= wf_bytes + xt_bytes) {
        unsigned short* wfb = (unsigned short*)d_ws;
        unsigned short* xtb = (unsigned short*)((char*)d_ws + wf_bytes);
        DeformConv2d_wfrag<<<144, 256, 0, stream>>>(weight, wfb);
        DeformConv2d_nhwc_bf16<<<4096, 256, 0, stream>>>(x, xtb);
        DeformConv2d_mfma<<<1024, 256, 0, stream>>>(offset, mask, wfb, xtb, out);
    } else {
        DeformConv2d_fallback<<<1024, 256, 0, stream>>>(x, offset, mask, weight, out);
    }
}

// Round 8
// 53.490 us; speedup vs baseline: 2.7338x; 1.0270x over previous
//
#include <hip/hip_runtime.h>

#define N_    4
#define CIN   64
#define COUT  64
#define H_    128
#define W_    128
#define HO_   128
#define WO_   128
#define K2_   9

typedef __attribute__((ext_vector_type(8))) short  short8;   // 8 bf16 (4 VGPRs)
typedef __attribute__((ext_vector_type(4))) float  f32x4;    // MFMA accumulator

__device__ __forceinline__ unsigned short f32_to_bf16_rne(float f) {
    unsigned int u = __float_as_uint(f);
    u += 0x7fffu + ((u >> 16) & 1u);
    return (unsigned short)(u >> 16);
}
__device__ __forceinline__ unsigned int pk_bf16(float lo, float hi) {
    unsigned int r;
    asm("v_cvt_pk_bf16_f32 %0, %1, %2" : "=v"(r) : "v"(lo), "v"(hi));
    return r;
}
__device__ __forceinline__ float bflo(unsigned int u) { return __uint_as_float(u << 16); }
__device__ __forceinline__ float bfhi(unsigned int u) { return __uint_as_float(u & 0xffff0000u); }

// bilinear combine of one packed pair (2 ci) across 4 corners -> packed bf16
__device__ __forceinline__ unsigned int comb1(
    unsigned int a00, unsigned int a01, unsigned int a10, unsigned int a11,
    float w00, float w01, float w10, float w11) {
    float lo = w00 * bflo(a00) + w01 * bflo(a01) + w10 * bflo(a10) + w11 * bflo(a11);
    float hi = w00 * bfhi(a00) + w01 * bfhi(a01) + w10 * bfhi(a10) + w11 * bfhi(a11);
    return pk_bf16(lo, hi);
}

// Pack weights into MFMA A-fragment order (bf16):
// wf[((k*4 + t)*2 + kk)*512 + lane*8 + j] = W[co = 16t + (lane&15)]
//                                            [ci = 32kk + (lane>>4)*8 + j] at tap k.
__global__ __launch_bounds__(256) void DeformConv2d_wfrag(
    const float* __restrict__ w, unsigned short* __restrict__ wf) {
    int i  = blockIdx.x * 256 + threadIdx.x;          // 0..36863
    int j  = i & 7;
    int l  = (i >> 3) & 63;
    int kk = (i >> 9) & 1;
    int t  = (i >> 10) & 3;
    int k  = i >> 12;
    int co = 16 * t + (l & 15);
    int ci = 32 * kk + ((l >> 4) << 3) + j;
    wf[i] = f32_to_bf16_rne(w[(co * CIN + ci) * K2_ + k]);
}

// One-shot NCHW f32 -> NHWC bf16: xtb[n][y][x][c].
__global__ __launch_bounds__(256) void DeformConv2d_nhwc_bf16(
    const float* __restrict__ x, unsigned short* __restrict__ xtb) {
    __shared__ float tile[64][17];
    const int b  = blockIdx.x;            // 4096 = n(4) * y(128) * xstrip(8)
    const int xs = (b & 7) << 4;
    const int y  = (b >> 3) & 127;
    const int n  = b >> 10;
    const int t  = threadIdx.x;
    const int xi = t & 15, c0 = t >> 4;
#pragma unroll
    for (int p = 0; p < 4; ++p) {
        int c = c0 + p * 16;
        tile[c][xi] = x[((size_t)(n * 64 + c) * 128 + y) * 128 + xs + xi];
    }
    __syncthreads();
    unsigned int* xq = (unsigned int*)xtb;
    const int cw2 = t & 31, x4 = t >> 5;   // x4: 0..7
#pragma unroll
    for (int q = 0; q < 2; ++q) {
        int xw = q * 8 + x4;
        unsigned int pk = pk_bf16(tile[2 * cw2][xw], tile[2 * cw2 + 1][xw]);
        xq[((size_t)((n * 128 + y) * 128) + xs + xw) * 32 + cw2] = pk;
    }
}

// Main kernel, round 8: 512 threads = 8 waves; wave wv owns (ho = hb+wv) x 16 wo
// x all 64 co. ALL 9 taps' A-fragments staged to LDS once (72 KB), ONE barrier;
// after that waves are fully independent (TLP latency hiding, no lockstep).
__global__ __launch_bounds__(512, 4) void DeformConv2d_mfma(
    const float* __restrict__ offset,       // [N,2*K2,HO,WO]
    const float* __restrict__ mask,         // [N,K2,HO,WO]
    const unsigned short* __restrict__ wf,  // bf16 A-fragments [9][512] short8
    const unsigned short* __restrict__ xtb, // bf16 NHWC [N,H,W,CIN]
    float* __restrict__ out)                // [N,COUT,HO,WO] f32
{
    __shared__ short8 Awl[K2_ * 512];       // 72 KB: all taps' A-fragments

    const int tid  = threadIdx.x;
    const int lane = tid & 63;
    const int wv   = tid >> 6;              // 0..7
    const int g    = lane >> 4;             // ci group
    const int pxw  = lane & 15;             // wo offset within wave
    const int ci0  = g * 8;

    // Bijective XCD chunk swizzle (512 % 8 == 0): 64 consecutive per XCD.
    const int raw = blockIdx.x;
    const int swz = (raw & 7) * 64 + (raw >> 3);
    const int n   = swz >> 7;               // 0..3
    const int r   = swz & 127;
    const int hb  = (r >> 3) << 3;          // 0..120 step 8
    const int wb  = (r & 7) << 4;           // 0..112 step 16
    const int ho  = hb + wv;
    const int wo  = wb + pxw;

    const unsigned short* xb = xtb + (size_t)n * (H_ * W_ * CIN);
    const short8* wfq = (const short8*)wf;  // [9][512]

    // ---- stage ALL taps' A-fragments; single barrier ----
#pragma unroll
    for (int e = 0; e < K2_; ++e) Awl[e * 512 + tid] = wfq[e * 512 + tid];

    f32x4 acc[4];
#pragma unroll
    for (int t = 0; t < 4; ++t) acc[t] = (f32x4){0.f, 0.f, 0.f, 0.f};

    // ---- preload ALL taps' params (27 independent loads) ----
    float dyv[K2_], dxv[K2_], mv[K2_];
#pragma unroll
    for (int k = 0; k < K2_; ++k) {
        dyv[k] = offset[((n * 18 + 2 * k)     * HO_ + ho) * WO_ + wo];
        dxv[k] = offset[((n * 18 + 2 * k + 1) * HO_ + ho) * WO_ + wo];
        mv[k]  = mask  [((n * 9  + k)         * HO_ + ho) * WO_ + wo];
    }

    // corner-load pipeline state (indices constant-folded by full unroll)
    uint4 ca[2][8];
    float cw[2][4];

    auto issue = [&](int k, int b) {
        const int KI = k / 3, KJ = k % 3;
        const float yy  = (float)(ho - 1 + KI) + dyv[k];
        const float xx  = (float)(wo - 1 + KJ) + dxv[k];
        const float y0f = floorf(yy), x0f = floorf(xx);
        const int   y0  = (int)y0f,  x0  = (int)x0f;
        const float fy  = yy - y0f,  fx  = xx - x0f;
        const bool yv0 = (y0 >= 0)  && (y0 < H_);
        const bool yv1 = (y0 >= -1) && (y0 < H_ - 1);
        const bool xv0 = (x0 >= 0)  && (x0 < W_);
        const bool xv1 = (x0 >= -1) && (x0 < W_ - 1);
        const float m   = mv[k];
        const float gy0 = (1.f - fy) * m, gy1 = fy * m;
        cw[b][0] = (yv0 && xv0) ? gy0 * (1.f - fx) : 0.f;
        cw[b][1] = (yv0 && xv1) ? gy0 * fx         : 0.f;
        cw[b][2] = (yv1 && xv0) ? gy1 * (1.f - fx) : 0.f;
        cw[b][3] = (yv1 && xv1) ? gy1 * fx         : 0.f;
        const int y0c = min(max(y0, 0), H_ - 1), y1c = min(max(y0 + 1, 0), H_ - 1);
        const int x0c = min(max(x0, 0), W_ - 1), x1c = min(max(x0 + 1, 0), W_ - 1);
        const uint4* p00 = (const uint4*)(xb + (y0c * W_ + x0c) * CIN + ci0);
        const uint4* p01 = (const uint4*)(xb + (y0c * W_ + x1c) * CIN + ci0);
        const uint4* p10 = (const uint4*)(xb + (y1c * W_ + x0c) * CIN + ci0);
        const uint4* p11 = (const uint4*)(xb + (y1c * W_ + x1c) * CIN + ci0);
        ca[b][0] = p00[0]; ca[b][1] = p01[0]; ca[b][2] = p10[0]; ca[b][3] = p11[0];
        ca[b][4] = p00[4]; ca[b][5] = p01[4]; ca[b][6] = p10[4]; ca[b][7] = p11[4];
    };

    issue(0, 0);
    __syncthreads();    // the ONLY barrier: Awl ready

#pragma unroll
    for (int k = 0; k < K2_; ++k) {
        if (k < 8) issue(k + 1, (k + 1) & 1);   // prefetch next tap's corners

        const int b = k & 1;
        const float w00 = cw[b][0], w01 = cw[b][1], w10 = cw[b][2], w11 = cw[b][3];
        union F8 { unsigned int u[4]; short8 s; } f0, f1;
        f0.u[0] = comb1(ca[b][0].x, ca[b][1].x, ca[b][2].x, ca[b][3].x, w00, w01, w10, w11);
        f0.u[1] = comb1(ca[b][0].y, ca[b][1].y, ca[b][2].y, ca[b][3].y, w00, w01, w10, w11);
        f0.u[2] = comb1(ca[b][0].z, ca[b][1].z, ca[b][2].z, ca[b][3].z, w00, w01, w10, w11);
        f0.u[3] = comb1(ca[b][0].w, ca[b][1].w, ca[b][2].w, ca[b][3].w, w00, w01, w10, w11);
        f1.u[0] = comb1(ca[b][4].x, ca[b][5].x, ca[b][6].x, ca[b][7].x, w00, w01, w10, w11);
        f1.u[1] = comb1(ca[b][4].y, ca[b][5].y, ca[b][6].y, ca[b][7].y, w00, w01, w10, w11);
        f1.u[2] = comb1(ca[b][4].z, ca[b][5].z, ca[b][6].z, ca[b][7].z, w00, w01, w10, w11);
        f1.u[3] = comb1(ca[b][4].w, ca[b][5].w, ca[b][6].w, ca[b][7].w, w00, w01, w10, w11);

        // MFMA: 4 co-tiles x 2 k-halves, A from LDS (read-only, no barrier needed)
#pragma unroll
        for (int t = 0; t < 4; ++t) {
            const short8 A0 = Awl[k * 512 + (t * 2 + 0) * 64 + lane];
            const short8 A1 = Awl[k * 512 + (t * 2 + 1) * 64 + lane];
            acc[t] = __builtin_amdgcn_mfma_f32_16x16x32_bf16(A0, f0.s, acc[t], 0, 0, 0);
            acc[t] = __builtin_amdgcn_mfma_f32_16x16x32_bf16(A1, f1.s, acc[t], 0, 0, 0);
        }
    }

    // epilogue: D col = lane&15 (px/wo), row = g*4 + reg (co within tile t)
#pragma unroll
    for (int t = 0; t < 4; ++t) {
#pragma unroll
        for (int rr = 0; rr < 4; ++rr) {
            out[((size_t)(n * COUT + 16 * t + g * 4 + rr) * HO_ + ho) * WO_ + wo] = acc[t][rr];
        }
    }
}

// fp32 fallback (no workspace): known-correct round-1 structure.
__global__ __launch_bounds__(256, 4) void DeformConv2d_fallback(
    const float* __restrict__ x, const float* __restrict__ offset,
    const float* __restrict__ mask, const float* __restrict__ weight,
    float* __restrict__ out)
{
    __shared__ float W_lds[CIN * COUT];
    __shared__ float S_lds[CIN * 68];
    __shared__ float cfy[64], cfx[64], cm[64];
    __shared__ int   cy0[64], cx0[64];

    const int tid = threadIdx.x;
    const int raw = blockIdx.x;
    const int swz = (raw & 7) * 128 + (raw >> 3);
    const int n   = swz >> 8;
    const int r   = swz & 255;
    const int hb  = (r >> 3) << 2;
    const int wb  = (r & 7) << 4;
    const int tr = tid >> 4, tc = tid & 15;

    float acc[4][4];
#pragma unroll
    for (int j = 0; j < 4; ++j)
#pragma unroll
        for (int i = 0; i < 4; ++i) acc[j][i] = 0.f;

    for (int k = 0; k < K2_; ++k) {
        __syncthreads();
        if (tid < 64) {
            const int px = tid, ho = hb + (px >> 4), wo = wb + (px & 15);
            const int ki = k / 3, kj = k % 3;
            const float dy = offset[((n * 18 + 2 * k)     * HO_ + ho) * WO_ + wo];
            const float dx = offset[((n * 18 + 2 * k + 1) * HO_ + ho) * WO_ + wo];
            const float m  = mask  [((n * 9  + k)         * HO_ + ho) * WO_ + wo];
            const float yy = (float)(ho - 1 + ki) + dy;
            const float xx = (float)(wo - 1 + kj) + dx;
            const float y0f = floorf(yy), x0f = floorf(xx);
            cy0[px] = (int)y0f; cx0[px] = (int)x0f;
            cfy[px] = yy - y0f; cfx[px] = xx - x0f; cm[px] = m;
        }
#pragma unroll
        for (int e = 0; e < 16; ++e) {
            int i = e * 256 + tid, ci = i >> 6, co = i & 63;
            W_lds[ci * 64 + co] = weight[(co * CIN + ci) * K2_ + k];
        }
        __syncthreads();
#pragma unroll
        for (int e = 0; e < 16; ++e) {
            int i = e * 256 + tid, ci = i >> 6, px = i & 63;
            int   y0 = cy0[px], x0 = cx0[px];
            float fy = cfy[px], fx = cfx[px], m = cm[px];
            const float* xc = x + (size_t)(n * CIN + ci) * (H_ * W_);
            bool yv0 = (y0 >= 0)  && (y0 < H_);
            bool yv1 = (y0 >= -1) && (y0 < H_ - 1);
            bool xv0 = (x0 >= 0)  && (x0 < W_);
            bool xv1 = (x0 >= -1) && (x0 < W_ - 1);
            float v00 = (yv0 && xv0) ? xc[y0 * W_ + x0]           : 0.f;
            float v01 = (yv0 && xv1) ? xc[y0 * W_ + x0 + 1]       : 0.f;
            float v10 = (yv1 && xv0) ? xc[(y0 + 1) * W_ + x0]     : 0.f;
            float v11 = (yv1 && xv1) ? xc[(y0 + 1) * W_ + x0 + 1] : 0.f;
            float v = (v00 * (1.f - fy) + v10 * fy) * (1.f - fx)
                    + (v01 * (1.f - fy) + v11 * fy) * fx;
            S_lds[ci * 68 + px] = v * m;
        }
        __syncthreads();
#pragma unroll 8
        for (int ci = 0; ci < CIN; ++ci) {
            const float4 a = *(const float4*)&W_lds[ci * 64 + tr * 4];
            const float4 b = *(const float4*)&S_lds[ci * 68 + tc * 4];
            acc[0][0] += a.x * b.x; acc[0][1] += a.x * b.y; acc[0][2] += a.x * b.z; acc[0][3] += a.x * b.w;
            acc[1][0] += a.y * b.x; acc[1][1] += a.y * b.y; acc[1][2] += a.y * b.z; acc[1][3] += a.y * b.w;
            acc[2][0] += a.z * b.x; acc[2][1] += a.z * b.y; acc[2][2] += a.z * b.z; acc[2][3] += a.z * b.w;
            acc[3][0] += a.w * b.x; acc[3][1] += a.w * b.y; acc[3][2] += a.w * b.z; acc[3][3] += a.w * b.w;
        }
    }
    const int co0 = tr * 4, hoE = hb + (tc >> 2), woE = wb + (tc & 3) * 4;
#pragma unroll
    for (int j = 0; j < 4; ++j) {
        float4 v; v.x = acc[j][0]; v.y = acc[j][1]; v.z = acc[j][2]; v.w = acc[j][3];
        *(float4*)&out[((size_t)(n * COUT + co0 + j) * HO_ + hoE) * WO_ + woE] = v;
    }
}

extern "C" void kernel_launch(void* const* d_in, const int* in_sizes, int n_in,
                              void* d_out, int out_size, void* d_ws, size_t ws_size,
                              hipStream_t stream) {
    const float* x      = (const float*)d_in[0];
    const float* offset = (const float*)d_in[1];
    const float* mask   = (const float*)d_in[2];
    const float* weight = (const float*)d_in[3];
    float* out = (float*)d_out;

    const size_t wf_bytes = (size_t)K2_ * 8 * 64 * 8 * sizeof(unsigned short);        // 73728
    const size_t xt_bytes = (size_t)N_ * H_ * W_ * CIN * sizeof(unsigned short);      // 8 MB

    if (ws_size >= wf_bytes + xt_bytes) {
        unsigned short* wfb = (unsigned short*)d_ws;
        unsigned short* xtb = (unsigned short*)((char*)d_ws + wf_bytes);
        DeformConv2d_wfrag<<<144, 256, 0, stream>>>(weight, wfb);
        DeformConv2d_nhwc_bf16<<<4096, 256, 0, stream>>>(x, xtb);
        DeformConv2d_mfma<<<512, 512, 0, stream>>>(offset, mask, wfb, xtb, out);
    } else {
        DeformConv2d_fallback<<<1024, 256, 0, stream>>>(x, offset, mask, weight, out);
    }
}

// Round 9
// 53.316 us; speedup vs baseline: 2.7428x; 1.0033x over previous
//
#include <hip/hip_runtime.h>

#define N_    4
#define CIN   64
#define COUT  64
#define H_    128
#define W_    128
#define HO_   128
#define WO_   128
#define K2_   9

typedef __attribute__((ext_vector_type(8))) short  short8;   // 8 bf16 (4 VGPRs)
typedef __attribute__((ext_vector_type(4))) float  f32x4;    // MFMA accumulator

__device__ __forceinline__ unsigned short f32_to_bf16_rne(float f) {
    unsigned int u = __float_as_uint(f);
    u += 0x7fffu + ((u >> 16) & 1u);
    return (unsigned short)(u >> 16);
}
__device__ __forceinline__ unsigned int pk_bf16(float lo, float hi) {
    unsigned int r;
    asm("v_cvt_pk_bf16_f32 %0, %1, %2" : "=v"(r) : "v"(lo), "v"(hi));
    return r;
}
__device__ __forceinline__ float bflo(unsigned int u) { return __uint_as_float(u << 16); }
__device__ __forceinline__ float bfhi(unsigned int u) { return __uint_as_float(u & 0xffff0000u); }

// bilinear combine of one packed pair (2 ci) across 4 corners -> packed bf16
__device__ __forceinline__ unsigned int comb1(
    unsigned int a00, unsigned int a01, unsigned int a10, unsigned int a11,
    float w00, float w01, float w10, float w11) {
    float lo = w00 * bflo(a00) + w01 * bflo(a01) + w10 * bflo(a10) + w11 * bflo(a11);
    float hi = w00 * bfhi(a00) + w01 * bfhi(a01) + w10 * bfhi(a10) + w11 * bfhi(a11);
    return pk_bf16(lo, hi);
}

// Pack weights into MFMA A-fragment order (bf16):
// wf[((k*4 + t)*2 + kk)*512 + lane*8 + j] = W[co = 16t + (lane&15)]
//                                            [ci = 32kk + (lane>>4)*8 + j] at tap k.
__global__ __launch_bounds__(256) void DeformConv2d_wfrag(
    const float* __restrict__ w, unsigned short* __restrict__ wf) {
    int i  = blockIdx.x * 256 + threadIdx.x;          // 0..36863
    int j  = i & 7;
    int l  = (i >> 3) & 63;
    int kk = (i >> 9) & 1;
    int t  = (i >> 10) & 3;
    int k  = i >> 12;
    int co = 16 * t + (l & 15);
    int ci = 32 * kk + ((l >> 4) << 3) + j;
    wf[i] = f32_to_bf16_rne(w[(co * CIN + ci) * K2_ + k]);
}

// One-shot NCHW f32 -> NHWC bf16: xtb[n][y][x][c].
__global__ __launch_bounds__(256) void DeformConv2d_nhwc_bf16(
    const float* __restrict__ x, unsigned short* __restrict__ xtb) {
    __shared__ float tile[64][17];
    const int b  = blockIdx.x;            // 4096 = n(4) * y(128) * xstrip(8)
    const int xs = (b & 7) << 4;
    const int y  = (b >> 3) & 127;
    const int n  = b >> 10;
    const int t  = threadIdx.x;
    const int xi = t & 15, c0 = t >> 4;
#pragma unroll
    for (int p = 0; p < 4; ++p) {
        int c = c0 + p * 16;
        tile[c][xi] = x[((size_t)(n * 64 + c) * 128 + y) * 128 + xs + xi];
    }
    __syncthreads();
    unsigned int* xq = (unsigned int*)xtb;
    const int cw2 = t & 31, x4 = t >> 5;   // x4: 0..7
#pragma unroll
    for (int q = 0; q < 2; ++q) {
        int xw = q * 8 + x4;
        unsigned int pk = pk_bf16(tile[2 * cw2][xw], tile[2 * cw2 + 1][xw]);
        xq[((size_t)((n * 128 + y) * 128) + xs + xw) * 32 + cw2] = pk;
    }
}

// Main kernel, round 9: 8 waves, one barrier, HALF-TAP software pipeline.
// Pipeline state sized (~90 VGPR) to fit under the 128-reg cap so the
// compiler keeps loads hoisted instead of sinking them (R7/R8 lesson).
__global__ __launch_bounds__(512, 4) void DeformConv2d_mfma(
    const float* __restrict__ offset,       // [N,2*K2,HO,WO]
    const float* __restrict__ mask,         // [N,K2,HO,WO]
    const unsigned short* __restrict__ wf,  // bf16 A-fragments [9][512] short8
    const unsigned short* __restrict__ xtb, // bf16 NHWC [N,H,W,CIN]
    float* __restrict__ out)                // [N,COUT,HO,WO] f32
{
    __shared__ short8 Awl[K2_ * 512];       // 72 KB: all taps' A-fragments

    const int tid  = threadIdx.x;
    const int lane = tid & 63;
    const int wv   = tid >> 6;              // 0..7
    const int g    = lane >> 4;             // ci group
    const int pxw  = lane & 15;             // wo offset within wave
    const int ci0  = g * 8;

    // Bijective XCD chunk swizzle (512 % 8 == 0): 64 consecutive per XCD.
    const int raw = blockIdx.x;
    const int swz = (raw & 7) * 64 + (raw >> 3);
    const int n   = swz >> 7;               // 0..3
    const int r   = swz & 127;
    const int hb  = (r >> 3) << 3;          // 0..120 step 8
    const int wb  = (r & 7) << 4;           // 0..112 step 16
    const int ho  = hb + wv;
    const int wo  = wb + pxw;

    const unsigned short* xb = xtb + (size_t)n * (H_ * W_ * CIN);
    const short8* wfq = (const short8*)wf;  // [9][512]

    // ---- stage ALL taps' A-fragments; single barrier ----
#pragma unroll
    for (int e = 0; e < K2_; ++e) Awl[e * 512 + tid] = wfq[e * 512 + tid];

    f32x4 acc[4];
#pragma unroll
    for (int t = 0; t < 4; ++t) acc[t] = (f32x4){0.f, 0.f, 0.f, 0.f};

    // ---- pipeline state (small on purpose) ----
    uint4 ca[2][4];       // [half-slot][corner] 16B each        = 32 VGPR
    float cwv[2][4];      // per-tap weights, indexed by k&1     =  8 VGPR
    int   bases[4];       // current-issuing tap's corner offsets =  4 VGPR
    float npdy, npdx, npm;                                      //  3 VGPR

    const int pofs = ho * WO_ + wo;

    auto loadp = [&](int k) {               // 3 coalesced dwords, 1 tap ahead
        npdy = offset[(n * 18 + 2 * k)     * (HO_ * WO_) + pofs];
        npdx = offset[(n * 18 + 2 * k + 1) * (HO_ * WO_) + pofs];
        npm  = mask  [(n * 9  + k)         * (HO_ * WO_) + pofs];
    };
    auto newtap = [&](int k) {              // consume np*, fill bases + cwv[k&1]
        const int KI = k / 3, KJ = k % 3;
        const float yy  = (float)(ho - 1 + KI) + npdy;
        const float xx  = (float)(wo - 1 + KJ) + npdx;
        const float y0f = floorf(yy), x0f = floorf(xx);
        const int   y0  = (int)y0f,  x0  = (int)x0f;
        const float fy  = yy - y0f,  fx  = xx - x0f;
        const bool yv0 = (y0 >= 0)  && (y0 < H_);
        const bool yv1 = (y0 >= -1) && (y0 < H_ - 1);
        const bool xv0 = (x0 >= 0)  && (x0 < W_);
        const bool xv1 = (x0 >= -1) && (x0 < W_ - 1);
        const float gy0 = (1.f - fy) * npm, gy1 = fy * npm;
        const int s = k & 1;
        cwv[s][0] = (yv0 && xv0) ? gy0 * (1.f - fx) : 0.f;
        cwv[s][1] = (yv0 && xv1) ? gy0 * fx         : 0.f;
        cwv[s][2] = (yv1 && xv0) ? gy1 * (1.f - fx) : 0.f;
        cwv[s][3] = (yv1 && xv1) ? gy1 * fx         : 0.f;
        const int y0c = min(max(y0, 0), H_ - 1), y1c = min(max(y0 + 1, 0), H_ - 1);
        const int x0c = min(max(x0, 0), W_ - 1), x1c = min(max(x0 + 1, 0), W_ - 1);
        bases[0] = (y0c * W_ + x0c) * CIN + ci0;
        bases[1] = (y0c * W_ + x1c) * CIN + ci0;
        bases[2] = (y1c * W_ + x0c) * CIN + ci0;
        bases[3] = (y1c * W_ + x1c) * CIN + ci0;
    };
    auto gather = [&](int slot, int kk) {   // 4 dwordx4 loads for one k-half
        const unsigned short* bp = xb + kk * 32;
#pragma unroll
        for (int c = 0; c < 4; ++c)
            ca[slot][c] = *(const uint4*)(bp + bases[c]);
    };

    // ---- prologue: tap 0 kk0 in flight, params for tap 1 in flight ----
    loadp(0);
    newtap(0);
    gather(0, 0);
    loadp(1);
    __syncthreads();    // the ONLY barrier: Awl ready

    // ---- 18 half-taps; issue half h+1 while combining half h ----
#pragma unroll
    for (int h = 0; h < 2 * K2_; ++h) {
        const int k = h >> 1, kk = h & 1, slot = h & 1;

        if (h < 2 * K2_ - 1) {
            const int hn = h + 1, kn = hn >> 1, kkn = hn & 1, sn = hn & 1;
            if (kkn == 0) {
                newtap(kn);             // consumes np* (loaded 2 halves ago)
                if (kn < K2_ - 1) loadp(kn + 1);
            }
            gather(sn, kkn);
        }

        const int s = k & 1;
        const float w00 = cwv[s][0], w01 = cwv[s][1], w10 = cwv[s][2], w11 = cwv[s][3];
        union F8 { unsigned int u[4]; short8 v; } f;
        f.u[0] = comb1(ca[slot][0].x, ca[slot][1].x, ca[slot][2].x, ca[slot][3].x, w00, w01, w10, w11);
        f.u[1] = comb1(ca[slot][0].y, ca[slot][1].y, ca[slot][2].y, ca[slot][3].y, w00, w01, w10, w11);
        f.u[2] = comb1(ca[slot][0].z, ca[slot][1].z, ca[slot][2].z, ca[slot][3].z, w00, w01, w10, w11);
        f.u[3] = comb1(ca[slot][0].w, ca[slot][1].w, ca[slot][2].w, ca[slot][3].w, w00, w01, w10, w11);

        // 4 MFMAs: co-tiles t=0..3, k-half kk
#pragma unroll
        for (int t = 0; t < 4; ++t) {
            const short8 A = Awl[k * 512 + (t * 2 + kk) * 64 + lane];
            acc[t] = __builtin_amdgcn_mfma_f32_16x16x32_bf16(A, f.v, acc[t], 0, 0, 0);
        }
    }

    // epilogue: D col = lane&15 (px/wo), row = g*4 + reg (co within tile t)
#pragma unroll
    for (int t = 0; t < 4; ++t) {
#pragma unroll
        for (int rr = 0; rr < 4; ++rr) {
            out[((size_t)(n * COUT + 16 * t + g * 4 + rr) * HO_ + ho) * WO_ + wo] = acc[t][rr];
        }
    }
}

// fp32 fallback (no workspace): known-correct round-1 structure.
__global__ __launch_bounds__(256, 4) void DeformConv2d_fallback(
    const float* __restrict__ x, const float* __restrict__ offset,
    const float* __restrict__ mask, const float* __restrict__ weight,
    float* __restrict__ out)
{
    __shared__ float W_lds[CIN * COUT];
    __shared__ float S_lds[CIN * 68];
    __shared__ float cfy[64], cfx[64], cm[64];
    __shared__ int   cy0[64], cx0[64];

    const int tid = threadIdx.x;
    const int raw = blockIdx.x;
    const int swz = (raw & 7) * 128 + (raw >> 3);
    const int n   = swz >> 8;
    const int r   = swz & 255;
    const int hb  = (r >> 3) << 2;
    const int wb  = (r & 7) << 4;
    const int tr = tid >> 4, tc = tid & 15;

    float acc[4][4];
#pragma unroll
    for (int j = 0; j < 4; ++j)
#pragma unroll
        for (int i = 0; i < 4; ++i) acc[j][i] = 0.f;

    for (int k = 0; k < K2_; ++k) {
        __syncthreads();
        if (tid < 64) {
            const int px = tid, ho = hb + (px >> 4), wo = wb + (px & 15);
            const int ki = k / 3, kj = k % 3;
            const float dy = offset[((n * 18 + 2 * k)     * HO_ + ho) * WO_ + wo];
            const float dx = offset[((n * 18 + 2 * k + 1) * HO_ + ho) * WO_ + wo];
            const float m  = mask  [((n * 9  + k)         * HO_ + ho) * WO_ + wo];
            const float yy = (float)(ho - 1 + ki) + dy;
            const float xx = (float)(wo - 1 + kj) + dx;
            const float y0f = floorf(yy), x0f = floorf(xx);
            cy0[px] = (int)y0f; cx0[px] = (int)x0f;
            cfy[px] = yy - y0f; cfx[px] = xx - x0f; cm[px] = m;
        }
#pragma unroll
        for (int e = 0; e < 16; ++e) {
            int i = e * 256 + tid, ci = i >> 6, co = i & 63;
            W_lds[ci * 64 + co] = weight[(co * CIN + ci) * K2_ + k];
        }
        __syncthreads();
#pragma unroll
        for (int e = 0; e < 16; ++e) {
            int i = e * 256 + tid, ci = i >> 6, px = i & 63;
            int   y0 = cy0[px], x0 = cx0[px];
            float fy = cfy[px], fx = cfx[px], m = cm[px];
            const float* xc = x + (size_t)(n * CIN + ci) * (H_ * W_);
            bool yv0 = (y0 >= 0)  && (y0 < H_);
            bool yv1 = (y0 >= -1) && (y0 < H_ - 1);
            bool xv0 = (x0 >= 0)  && (x0 < W_);
            bool xv1 = (x0 >= -1) && (x0 < W_ - 1);
            float v00 = (yv0 && xv0) ? xc[y0 * W_ + x0]           : 0.f;
            float v01 = (yv0 && xv1) ? xc[y0 * W_ + x0 + 1]       : 0.f;
            float v10 = (yv1 && xv0) ? xc[(y0 + 1) * W_ + x0]     : 0.f;
            float v11 = (yv1 && xv1) ? xc[(y0 + 1) * W_ + x0 + 1] : 0.f;
            float v = (v00 * (1.f - fy) + v10 * fy) * (1.f - fx)
                    + (v01 * (1.f - fy) + v11 * fy) * fx;
            S_lds[ci * 68 + px] = v * m;
        }
        __syncthreads();
#pragma unroll 8
        for (int ci = 0; ci < CIN; ++ci) {
            const float4 a = *(const float4*)&W_lds[ci * 64 + tr * 4];
            const float4 b = *(const float4*)&S_lds[ci * 68 + tc * 4];
            acc[0][0] += a.x * b.x; acc[0][1] += a.x * b.y; acc[0][2] += a.x * b.z; acc[0][3] += a.x * b.w;
            acc[1][0] += a.y * b.x; acc[1][1] += a.y * b.y; acc[1][2] += a.y * b.z; acc[1][3] += a.y * b.w;
            acc[2][0] += a.z * b.x; acc[2][1] += a.z * b.y; acc[2][2] += a.z * b.z; acc[2][3] += a.z * b.w;
            acc[3][0] += a.w * b.x; acc[3][1] += a.w * b.y; acc[3][2] += a.w * b.z; acc[3][3] += a.w * b.w;
        }
    }
    const int co0 = tr * 4, hoE = hb + (tc >> 2), woE = wb + (tc & 3) * 4;
#pragma unroll
    for (int j = 0; j < 4; ++j) {
        float4 v; v.x = acc[j][0]; v.y = acc[j][1]; v.z = acc[j][2]; v.w = acc[j][3];
        *(float4*)&out[((size_t)(n * COUT + co0 + j) * HO_ + hoE) * WO_ + woE] = v;
    }
}

extern "C" void kernel_launch(void* const* d_in, const int* in_sizes, int n_in,
                              void* d_out, int out_size, void* d_ws, size_t ws_size,
                              hipStream_t stream) {
    const float* x      = (const float*)d_in[0];
    const float* offset = (const float*)d_in[1];
    const float* mask   = (const float*)d_in[2];
    const float* weight = (const float*)d_in[3];
    float* out = (float*)d_out;

    const size_t wf_bytes = (size_t)K2_ * 8 * 64 * 8 * sizeof(unsigned short);        // 73728
    const size_t xt_bytes = (size_t)N_ * H_ * W_ * CIN * sizeof(unsigned short);      // 8 MB

    if (ws_size >= wf_bytes + xt_bytes) {
        unsigned short* wfb = (unsigned short*)d_ws;
        unsigned short* xtb = (unsigned short*)((char*)d_ws + wf_bytes);
        DeformConv2d_wfrag<<<144, 256, 0, stream>>>(weight, wfb);
        DeformConv2d_nhwc_bf16<<<4096, 256, 0, stream>>>(x, xtb);
        DeformConv2d_mfma<<<512, 512, 0, stream>>>(offset, mask, wfb, xtb, out);
    } else {
        DeformConv2d_fallback<<<1024, 256, 0, stream>>>(x, offset, mask, weight, out);
    }
}

// Round 11
// 38.782 us; speedup vs baseline: 3.7707x; 1.3747x over previous
//
#include <hip/hip_runtime.h>

#define N_    4
#define CIN   64
#define COUT  64
#define H_    128
#define W_    128
#define HO_   128
#define WO_   128
#define K2_   9

// staged halo region: rows [hb-5, hb+12] (18), cols [wb-5, wb+20] (26)
#define RROWS 18
#define RCOLS 26

typedef __attribute__((ext_vector_type(8))) short  short8;   // 8 bf16 (4 VGPRs)
typedef __attribute__((ext_vector_type(4))) float  f32x4;    // MFMA accumulator

__device__ __forceinline__ unsigned short f32_to_bf16_rne(float f) {
    unsigned int u = __float_as_uint(f);
    u += 0x7fffu + ((u >> 16) & 1u);
    return (unsigned short)(u >> 16);
}
__device__ __forceinline__ unsigned int pk_bf16(float lo, float hi) {
    unsigned int r;
    asm("v_cvt_pk_bf16_f32 %0, %1, %2" : "=v"(r) : "v"(lo), "v"(hi));
    return r;
}
__device__ __forceinline__ float bflo(unsigned int u) { return __uint_as_float(u << 16); }
__device__ __forceinline__ float bfhi(unsigned int u) { return __uint_as_float(u & 0xffff0000u); }

// bilinear combine of one packed pair (2 ci) across 4 corners -> packed bf16
__device__ __forceinline__ unsigned int comb1(
    unsigned int a00, unsigned int a01, unsigned int a10, unsigned int a11,
    float w00, float w01, float w10, float w11) {
    float lo = w00 * bflo(a00) + w01 * bflo(a01) + w10 * bflo(a10) + w11 * bflo(a11);
    float hi = w00 * bfhi(a00) + w01 * bfhi(a01) + w10 * bfhi(a10) + w11 * bfhi(a11);
    return pk_bf16(lo, hi);
}

// single source of truth for the region swizzle: px-block p, 16B-chunk c (0..7)
__device__ __forceinline__ int reg_byteoff(int p, int c) {
    return p * 128 + (((c ^ p) & 7) << 4);
}

// Pack weights into MFMA A-fragment order (bf16):
// wf[((k*4 + t)*2 + kk)*512 + lane*8 + j] = W[co = 16t + (lane&15)]
//                                            [ci = 32kk + (lane>>4)*8 + j] at tap k.
__global__ __launch_bounds__(256) void DeformConv2d_wfrag(
    const float* __restrict__ w, unsigned short* __restrict__ wf) {
    int i  = blockIdx.x * 256 + threadIdx.x;          // 0..36863
    int j  = i & 7;
    int l  = (i >> 3) & 63;
    int kk = (i >> 9) & 1;
    int t  = (i >> 10) & 3;
    int k  = i >> 12;
    int co = 16 * t + (l & 15);
    int ci = 32 * kk + ((l >> 4) << 3) + j;
    wf[i] = f32_to_bf16_rne(w[(co * CIN + ci) * K2_ + k]);
}

// One-shot NCHW f32 -> NHWC bf16: xtb[n][y][x][c].
__global__ __launch_bounds__(256) void DeformConv2d_nhwc_bf16(
    const float* __restrict__ x, unsigned short* __restrict__ xtb) {
    __shared__ float tile[64][17];
    const int b  = blockIdx.x;            // 4096 = n(4) * y(128) * xstrip(8)
    const int xs = (b & 7) << 4;
    const int y  = (b >> 3) & 127;
    const int n  = b >> 10;
    const int t  = threadIdx.x;
    const int xi = t & 15, c0 = t >> 4;
#pragma unroll
    for (int p = 0; p < 4; ++p) {
        int c = c0 + p * 16;
        tile[c][xi] = x[((size_t)(n * 64 + c) * 128 + y) * 128 + xs + xi];
    }
    __syncthreads();
    unsigned int* xq = (unsigned int*)xtb;
    const int cw2 = t & 31, x4 = t >> 5;   // x4: 0..7
#pragma unroll
    for (int q = 0; q < 2; ++q) {
        int xw = q * 8 + x4;
        unsigned int pk = pk_bf16(tile[2 * cw2][xw], tile[2 * cw2 + 1][xw]);
        xq[((size_t)((n * 128 + y) * 128) + xs + xw) * 32 + cw2] = pk;
    }
}

// Round 11: LDS-gather. R9 wave layout (8 waves = 8 ho rows x 16 wo, full ci
// per wave). The 18x26-px NHWC halo region is staged to LDS once; corner
// gathers become swizzled ds_read_b128 (bank-spread) instead of TA-serialized
// global gathers. Rare out-of-region samples (|offset|>~4) take a wave-uniform
// global fallback. A-fragments: per-tap 16KB LDS double-buffer (R6 pattern).
__global__ __launch_bounds__(512, 4) void DeformConv2d_mfma(
    const float* __restrict__ offset,       // [N,2*K2,HO,WO]
    const float* __restrict__ mask,         // [N,K2,HO,WO]
    const unsigned short* __restrict__ wf,  // bf16 A-fragments [9][512] short8
    const unsigned short* __restrict__ xtb, // bf16 NHWC [N,H,W,CIN]
    float* __restrict__ out)                // [N,COUT,HO,WO] f32
{
    __shared__ short8 Adbuf[2][512];            // 16 KB A double buffer
    __shared__ uint4  Xr4[RROWS * RCOLS * 8];   // 59904 B halo region

    const int tid  = threadIdx.x;
    const int lane = tid & 63;
    const int wv   = tid >> 6;              // 0..7 -> ho row
    const int g    = lane >> 4;             // ci group
    const int pxw  = lane & 15;             // wo offset within wave
    const int ci0  = g * 8;

    // Bijective XCD chunk swizzle (512 % 8 == 0): 64 consecutive per XCD.
    const int raw = blockIdx.x;
    const int swz = (raw & 7) * 64 + (raw >> 3);
    const int n   = swz >> 7;               // 0..3
    const int r   = swz & 127;
    const int hb  = (r >> 3) << 3;          // 0..120 step 8
    const int wb  = (r & 7) << 4;           // 0..112 step 16
    const int ho  = hb + wv;
    const int wo  = wb + pxw;
    const int rowbase = hb - 5;
    const int colbase = wb - 5;

    const unsigned short* xb = xtb + (size_t)n * (H_ * W_ * CIN);
    const short8* wfq = (const short8*)wf;  // [9][512]
    char* XrB = (char*)Xr4;

    // ---- stage halo region (coalesced) + tap-0 A-fragments ----
    {
        const int NCHUNK = RROWS * RCOLS * 8;   // 3744
#pragma unroll
        for (int e = 0; e < 8; ++e) {
            int q = e * 512 + tid;
            if (q < NCHUNK) {
                int p = q >> 3, c = q & 7;
                int i = p / RCOLS, j = p - i * RCOLS;
                int sy = min(max(rowbase + i, 0), H_ - 1);
                int sx = min(max(colbase + j, 0), W_ - 1);
                const uint4 v = *(const uint4*)(xb + (sy * W_ + sx) * CIN + c * 8);
                *(uint4*)(XrB + reg_byteoff(p, c)) = v;
            }
        }
        Adbuf[0][tid] = wfq[tid];
    }

    f32x4 acc[4];
#pragma unroll
    for (int t = 0; t < 4; ++t) acc[t] = (f32x4){0.f, 0.f, 0.f, 0.f};

    const int pofs = ho * WO_ + wo;
    float npdy = offset[(n * 18 + 0) * (HO_ * WO_) + pofs];
    float npdx = offset[(n * 18 + 1) * (HO_ * WO_) + pofs];
    float npm  = mask  [(n * 9  + 0) * (HO_ * WO_) + pofs];

    __syncthreads();    // region + A0 ready

#pragma unroll
    for (int k = 0; k < K2_; ++k) {
        // A prefetch for next tap (write-late after MFMA; R6 discipline)
        short8 sA;
        if (k < K2_ - 1) sA = wfq[(k + 1) * 512 + tid];

        // consume np* for tap k
        const int KI = k / 3, KJ = k % 3;
        const float yy  = (float)(ho - 1 + KI) + npdy;
        const float xx  = (float)(wo - 1 + KJ) + npdx;
        const float y0f = floorf(yy), x0f = floorf(xx);
        const int   y0  = (int)y0f,  x0  = (int)x0f;
        const float fy  = yy - y0f,  fx  = xx - x0f;
        const bool yv0 = (y0 >= 0)  && (y0 < H_);
        const bool yv1 = (y0 >= -1) && (y0 < H_ - 1);
        const bool xv0 = (x0 >= 0)  && (x0 < W_);
        const bool xv1 = (x0 >= -1) && (x0 < W_ - 1);
        const float gy0 = (1.f - fy) * npm, gy1 = fy * npm;
        const float w00 = (yv0 && xv0) ? gy0 * (1.f - fx) : 0.f;
        const float w01 = (yv0 && xv1) ? gy0 * fx         : 0.f;
        const float w10 = (yv1 && xv0) ? gy1 * (1.f - fx) : 0.f;
        const float w11 = (yv1 && xv1) ? gy1 * fx         : 0.f;
        const int y0c = min(max(y0, 0), H_ - 1), y1c = min(max(y0 + 1, 0), H_ - 1);
        const int x0c = min(max(x0, 0), W_ - 1), x1c = min(max(x0 + 1, 0), W_ - 1);

        // params for next tap
        if (k < K2_ - 1) {
            npdy = offset[(n * 18 + 2 * (k + 1))     * (HO_ * WO_) + pofs];
            npdx = offset[(n * 18 + 2 * (k + 1) + 1) * (HO_ * WO_) + pofs];
            npm  = mask  [(n * 9  + (k + 1))         * (HO_ * WO_) + pofs];
        }

        // ---- 4 corners from LDS region (both ci halves), rare global fallback ----
        uint4 cva[4], cvb[4];   // [corner] kk=0 / kk=1
        const int cys[2] = { y0c, y1c };
        const int cxs[2] = { x0c, x1c };
#pragma unroll
        for (int cy_i = 0; cy_i < 2; ++cy_i) {
#pragma unroll
            for (int cx_i = 0; cx_i < 2; ++cx_i) {
                const int ci_ = cy_i * 2 + cx_i;
                const int cy = cys[cy_i], cx = cxs[cx_i];
                const int ry = cy - rowbase, rx = cx - colbase;
                const bool in = ((unsigned)ry < (unsigned)RROWS) &&
                                ((unsigned)rx < (unsigned)RCOLS);
                const int p = min(max(ry, 0), RROWS - 1) * RCOLS + min(max(rx, 0), RCOLS - 1);
                uint4 lv0 = *(const uint4*)(XrB + reg_byteoff(p, g));
                uint4 lv1 = *(const uint4*)(XrB + reg_byteoff(p, 4 + g));
                if (!__all((int)in)) {          // wave-uniform rare path
                    const unsigned short* gp = xb + (cy * W_ + cx) * CIN + ci0;
                    uint4 gv0 = *(const uint4*)(gp);
                    uint4 gv1 = *(const uint4*)(gp + 32);
                    if (!in) { lv0 = gv0; lv1 = gv1; }   // exec-masked per lane
                }
                cva[ci_] = lv0;
                cvb[ci_] = lv1;
            }
        }

        // ---- combine -> B fragments (bf16) ----
        union F8 { unsigned int u[4]; short8 s; } f0, f1;
        f0.u[0] = comb1(cva[0].x, cva[1].x, cva[2].x, cva[3].x, w00, w01, w10, w11);
        f0.u[1] = comb1(cva[0].y, cva[1].y, cva[2].y, cva[3].y, w00, w01, w10, w11);
        f0.u[2] = comb1(cva[0].z, cva[1].z, cva[2].z, cva[3].z, w00, w01, w10, w11);
        f0.u[3] = comb1(cva[0].w, cva[1].w, cva[2].w, cva[3].w, w00, w01, w10, w11);
        f1.u[0] = comb1(cvb[0].x, cvb[1].x, cvb[2].x, cvb[3].x, w00, w01, w10, w11);
        f1.u[1] = comb1(cvb[0].y, cvb[1].y, cvb[2].y, cvb[3].y, w00, w01, w10, w11);
        f1.u[2] = comb1(cvb[0].z, cvb[1].z, cvb[2].z, cvb[3].z, w00, w01, w10, w11);
        f1.u[3] = comb1(cvb[0].w, cvb[1].w, cvb[2].w, cvb[3].w, w00, w01, w10, w11);

        // ---- MFMA: 4 co-tiles x 2 k-halves ----
#pragma unroll
        for (int t = 0; t < 4; ++t) {
            const short8 A0 = Adbuf[k & 1][(t * 2 + 0) * 64 + lane];
            const short8 A1 = Adbuf[k & 1][(t * 2 + 1) * 64 + lane];
            acc[t] = __builtin_amdgcn_mfma_f32_16x16x32_bf16(A0, f0.s, acc[t], 0, 0, 0);
            acc[t] = __builtin_amdgcn_mfma_f32_16x16x32_bf16(A1, f1.s, acc[t], 0, 0, 0);
        }

        // write-late A-stage + single barrier per tap
        if (k < K2_ - 1) {
            Adbuf[(k + 1) & 1][tid] = sA;
            __syncthreads();
        }
    }

    // epilogue: D col = lane&15 (px/wo), row = g*4 + reg (co within tile t)
#pragma unroll
    for (int t = 0; t < 4; ++t) {
#pragma unroll
        for (int rr = 0; rr < 4; ++rr) {
            out[((size_t)(n * COUT + 16 * t + g * 4 + rr) * HO_ + ho) * WO_ + wo] = acc[t][rr];
        }
    }
}

// fp32 fallback (no workspace): known-correct round-1 structure.
__global__ __launch_bounds__(256, 4) void DeformConv2d_fallback(
    const float* __restrict__ x, const float* __restrict__ offset,
    const float* __restrict__ mask, const float* __restrict__ weight,
    float* __restrict__ out)
{
    __shared__ float W_lds[CIN * COUT];
    __shared__ float S_lds[CIN * 68];
    __shared__ float cfy[64], cfx[64], cm[64];
    __shared__ int   cy0[64], cx0[64];

    const int tid = threadIdx.x;
    const int raw = blockIdx.x;
    const int swz = (raw & 7) * 128 + (raw >> 3);
    const int n   = swz >> 8;
    const int r   = swz & 255;
    const int hb  = (r >> 3) << 2;
    const int wb  = (r & 7) << 4;
    const int tr = tid >> 4, tc = tid & 15;

    float acc[4][4];
#pragma unroll
    for (int j = 0; j < 4; ++j)
#pragma unroll
        for (int i = 0; i < 4; ++i) acc[j][i] = 0.f;

    for (int k = 0; k < K2_; ++k) {
        __syncthreads();
        if (tid < 64) {
            const int px = tid, ho = hb + (px >> 4), wo = wb + (px & 15);
            const int ki = k / 3, kj = k % 3;
            const float dy = offset[((n * 18 + 2 * k)     * HO_ + ho) * WO_ + wo];
            const float dx = offset[((n * 18 + 2 * k + 1) * HO_ + ho) * WO_ + wo];
            const float m  = mask  [((n * 9  + k)         * HO_ + ho) * WO_ + wo];
            const float yy = (float)(ho - 1 + ki) + dy;
            const float xx = (float)(wo - 1 + kj) + dx;
            const float y0f = floorf(yy), x0f = floorf(xx);
            cy0[px] = (int)y0f; cx0[px] = (int)x0f;
            cfy[px] = yy - y0f; cfx[px] = xx - x0f; cm[px] = m;
        }
#pragma unroll
        for (int e = 0; e < 16; ++e) {
            int i = e * 256 + tid, ci = i >> 6, co = i & 63;
            W_lds[ci * 64 + co] = weight[(co * CIN + ci) * K2_ + k];
        }
        __syncthreads();
#pragma unroll
        for (int e = 0; e < 16; ++e) {
            int i = e * 256 + tid, ci = i >> 6, px = i & 63;
            int   y0 = cy0[px], x0 = cx0[px];
            float fy = cfy[px], fx = cfx[px], m = cm[px];
            const float* xc = x + (size_t)(n * CIN + ci) * (H_ * W_);
            bool yv0 = (y0 >= 0)  && (y0 < H_);
            bool yv1 = (y0 >= -1) && (y0 < H_ - 1);
            bool xv0 = (x0 >= 0)  && (x0 < W_);
            bool xv1 = (x0 >= -1) && (x0 < W_ - 1);
            float v00 = (yv0 && xv0) ? xc[y0 * W_ + x0]           : 0.f;
            float v01 = (yv0 && xv1) ? xc[y0 * W_ + x0 + 1]       : 0.f;
            float v10 = (yv1 && xv0) ? xc[(y0 + 1) * W_ + x0]     : 0.f;
            float v11 = (yv1 && xv1) ? xc[(y0 + 1) * W_ + x0 + 1] : 0.f;
            float v = (v00 * (1.f - fy) + v10 * fy) * (1.f - fx)
                    + (v01 * (1.f - fy) + v11 * fy) * fx;
            S_lds[ci * 68 + px] = v * m;
        }
        __syncthreads();
#pragma unroll 8
        for (int ci = 0; ci < CIN; ++ci) {
            const float4 a = *(const float4*)&W_lds[ci * 64 + tr * 4];
            const float4 b = *(const float4*)&S_lds[ci * 68 + tc * 4];
            acc[0][0] += a.x * b.x; acc[0][1] += a.x * b.y; acc[0][2] += a.x * b.z; acc[0][3] += a.x * b.w;
            acc[1][0] += a.y * b.x; acc[1][1] += a.y * b.y; acc[1][2] += a.y * b.z; acc[1][3] += a.y * b.w;
            acc[2][0] += a.z * b.x; acc[2][1] += a.z * b.y; acc[2][2] += a.z * b.z; acc[2][3] += a.z * b.w;
            acc[3][0] += a.w * b.x; acc[3][1] += a.w * b.y; acc[3][2] += a.w * b.z; acc[3][3] += a.w * b.w;
        }
    }
    const int co0 = tr * 4, hoE = hb + (tc >> 2), woE = wb + (tc & 3) * 4;
#pragma unroll
    for (int j = 0; j < 4; ++j) {
        float4 v; v.x = acc[j][0]; v.y = acc[j][1]; v.z = acc[j][2]; v.w = acc[j][3];
        *(float4*)&out[((size_t)(n * COUT + co0 + j) * HO_ + hoE) * WO_ + woE] = v;
    }
}

extern "C" void kernel_launch(void* const* d_in, const int* in_sizes, int n_in,
                              void* d_out, int out_size, void* d_ws, size_t ws_size,
                              hipStream_t stream) {
    const float* x      = (const float*)d_in[0];
    const float* offset = (const float*)d_in[1];
    const float* mask   = (const float*)d_in[2];
    const float* weight = (const float*)d_in[3];
    float* out = (float*)d_out;

    const size_t wf_bytes = (size_t)K2_ * 8 * 64 * 8 * sizeof(unsigned short);        // 73728
    const size_t xt_bytes = (size_t)N_ * H_ * W_ * CIN * sizeof(unsigned short);      // 8 MB

    if (ws_size >= wf_bytes + xt_bytes) {
        unsigned short* wfb = (unsigned short*)d_ws;
        unsigned short* xtb = (unsigned short*)((char*)d_ws + wf_bytes);
        DeformConv2d_wfrag<<<144, 256, 0, stream>>>(weight, wfb);
        DeformConv2d_nhwc_bf16<<<4096, 256, 0, stream>>>(x, xtb);
        DeformConv2d_mfma<<<512, 512, 0, stream>>>(offset, mask, wfb, xtb, out);
    } else {
        DeformConv2d_fallback<<<1024, 256, 0, stream>>>(x, offset, mask, weight, out);
    }
}

// Round 14
// 33.404 us; speedup vs baseline: 4.3778x; 1.1610x over previous
//
#include <hip/hip_runtime.h>

#define N_    4
#define CIN   64
#define COUT  64
#define H_    128
#define W_    128
#define HO_   128
#define WO_   128
#define K2_   9

// staged halo region: rows [hb-5, hb+12] (18), cols [wb-5, wb+20] (26)
#define RROWS 18
#define RCOLS 26

typedef __attribute__((ext_vector_type(8))) short  short8;   // 8 bf16 (4 VGPRs)
typedef __attribute__((ext_vector_type(4))) float  f32x4;    // MFMA accumulator

__device__ __forceinline__ unsigned short f32_to_bf16_rne(float f) {
    unsigned int u = __float_as_uint(f);
    u += 0x7fffu + ((u >> 16) & 1u);
    return (unsigned short)(u >> 16);
}
__device__ __forceinline__ unsigned int pk_bf16(float lo, float hi) {
    unsigned int r;
    asm("v_cvt_pk_bf16_f32 %0, %1, %2" : "=v"(r) : "v"(lo), "v"(hi));
    return r;
}
__device__ __forceinline__ float bflo(unsigned int u) { return __uint_as_float(u << 16); }
__device__ __forceinline__ float bfhi(unsigned int u) { return __uint_as_float(u & 0xffff0000u); }

// bilinear combine of one packed pair (2 ci) across 4 corners -> packed bf16
__device__ __forceinline__ unsigned int comb1(
    unsigned int a00, unsigned int a01, unsigned int a10, unsigned int a11,
    float w00, float w01, float w10, float w11) {
    float lo = w00 * bflo(a00) + w01 * bflo(a01) + w10 * bflo(a10) + w11 * bflo(a11);
    float hi = w00 * bfhi(a00) + w01 * bfhi(a01) + w10 * bfhi(a10) + w11 * bfhi(a11);
    return pk_bf16(lo, hi);
}

// single source of truth for the region swizzle: px-block p, 16B-chunk c (0..7)
__device__ __forceinline__ int reg_byteoff(int p, int c) {
    return p * 128 + (((c ^ p) & 7) << 4);
}

// Fused prep: blocks [0,4096) do NCHW f32 -> NHWC bf16; blocks [4096,4240)
// pack weights into MFMA A-fragment order. One launch instead of two.
__global__ __launch_bounds__(256) void DeformConv2d_prep(
    const float* __restrict__ x, const float* __restrict__ w,
    unsigned short* __restrict__ xtb, unsigned short* __restrict__ wfb) {
    const int b = blockIdx.x;
    if (b < 4096) {
        __shared__ float tile[64][17];
        const int xs = (b & 7) << 4;
        const int y  = (b >> 3) & 127;
        const int n  = b >> 10;
        const int t  = threadIdx.x;
        const int xi = t & 15, c0 = t >> 4;
#pragma unroll
        for (int p = 0; p < 4; ++p) {
            int c = c0 + p * 16;
            tile[c][xi] = x[((size_t)(n * 64 + c) * 128 + y) * 128 + xs + xi];
        }
        __syncthreads();
        unsigned int* xq = (unsigned int*)xtb;
        const int cw2 = t & 31, x4 = t >> 5;   // x4: 0..7
#pragma unroll
        for (int q = 0; q < 2; ++q) {
            int xw = q * 8 + x4;
            unsigned int pk = pk_bf16(tile[2 * cw2][xw], tile[2 * cw2 + 1][xw]);
            xq[((size_t)((n * 128 + y) * 128) + xs + xw) * 32 + cw2] = pk;
        }
    } else {
        // wf[((k*4 + t)*2 + kk)*512 + lane*8 + j] = W[co=16t+(l&15)][ci=32kk+(l>>4)*8+j] at tap k
        int i = (b - 4096) * 256 + threadIdx.x;       // 0..36863
        if (i < COUT * CIN * K2_) {
            int j  = i & 7;
            int l  = (i >> 3) & 63;
            int kk = (i >> 9) & 1;
            int t  = (i >> 10) & 3;
            int k  = i >> 12;
            int co = 16 * t + (l & 15);
            int ci = 32 * kk + ((l >> 4) << 3) + j;
            wfb[i] = f32_to_bf16_rne(w[(co * CIN + ci) * K2_ + k]);
        }
    }
}

// Main kernel: VERBATIM round-11 (passed, 38.8us total). LDS-gather halo
// region + per-tap A-fragment LDS double buffer with write-late + barrier.
__global__ __launch_bounds__(512, 4) void DeformConv2d_mfma(
    const float* __restrict__ offset,       // [N,2*K2,HO,WO]
    const float* __restrict__ mask,         // [N,K2,HO,WO]
    const unsigned short* __restrict__ wf,  // bf16 A-fragments [9][512] short8
    const unsigned short* __restrict__ xtb, // bf16 NHWC [N,H,W,CIN]
    float* __restrict__ out)                // [N,COUT,HO,WO] f32
{
    __shared__ short8 Adbuf[2][512];            // 16 KB A double buffer
    __shared__ uint4  Xr4[RROWS * RCOLS * 8];   // 59904 B halo region

    const int tid  = threadIdx.x;
    const int lane = tid & 63;
    const int wv   = tid >> 6;              // 0..7 -> ho row
    const int g    = lane >> 4;             // ci group
    const int pxw  = lane & 15;             // wo offset within wave
    const int ci0  = g * 8;

    // Bijective XCD chunk swizzle (512 % 8 == 0): 64 consecutive per XCD.
    const int raw = blockIdx.x;
    const int swz = (raw & 7) * 64 + (raw >> 3);
    const int n   = swz >> 7;               // 0..3
    const int r   = swz & 127;
    const int hb  = (r >> 3) << 3;          // 0..120 step 8
    const int wb  = (r & 7) << 4;           // 0..112 step 16
    const int ho  = hb + wv;
    const int wo  = wb + pxw;
    const int rowbase = hb - 5;
    const int colbase = wb - 5;

    const unsigned short* xb = xtb + (size_t)n * (H_ * W_ * CIN);
    const short8* wfq = (const short8*)wf;  // [9][512]
    char* XrB = (char*)Xr4;

    // ---- stage halo region (coalesced) + tap-0 A-fragments ----
    {
        const int NCHUNK = RROWS * RCOLS * 8;   // 3744
#pragma unroll
        for (int e = 0; e < 8; ++e) {
            int q = e * 512 + tid;
            if (q < NCHUNK) {
                int p = q >> 3, c = q & 7;
                int i = p / RCOLS, j = p - i * RCOLS;
                int sy = min(max(rowbase + i, 0), H_ - 1);
                int sx = min(max(colbase + j, 0), W_ - 1);
                const uint4 v = *(const uint4*)(xb + (sy * W_ + sx) * CIN + c * 8);
                *(uint4*)(XrB + reg_byteoff(p, c)) = v;
            }
        }
        Adbuf[0][tid] = wfq[tid];
    }

    f32x4 acc[4];
#pragma unroll
    for (int t = 0; t < 4; ++t) acc[t] = (f32x4){0.f, 0.f, 0.f, 0.f};

    const int pofs = ho * WO_ + wo;
    float npdy = offset[(n * 18 + 0) * (HO_ * WO_) + pofs];
    float npdx = offset[(n * 18 + 1) * (HO_ * WO_) + pofs];
    float npm  = mask  [(n * 9  + 0) * (HO_ * WO_) + pofs];

    __syncthreads();    // region + A0 ready

#pragma unroll
    for (int k = 0; k < K2_; ++k) {
        // A prefetch for next tap (write-late after MFMA; R6 discipline)
        short8 sA;
        if (k < K2_ - 1) sA = wfq[(k + 1) * 512 + tid];

        // consume np* for tap k
        const int KI = k / 3, KJ = k % 3;
        const float yy  = (float)(ho - 1 + KI) + npdy;
        const float xx  = (float)(wo - 1 + KJ) + npdx;
        const float y0f = floorf(yy), x0f = floorf(xx);
        const int   y0  = (int)y0f,  x0  = (int)x0f;
        const float fy  = yy - y0f,  fx  = xx - x0f;
        const bool yv0 = (y0 >= 0)  && (y0 < H_);
        const bool yv1 = (y0 >= -1) && (y0 < H_ - 1);
        const bool xv0 = (x0 >= 0)  && (x0 < W_);
        const bool xv1 = (x0 >= -1) && (x0 < W_ - 1);
        const float gy0 = (1.f - fy) * npm, gy1 = fy * npm;
        const float w00 = (yv0 && xv0) ? gy0 * (1.f - fx) : 0.f;
        const float w01 = (yv0 && xv1) ? gy0 * fx         : 0.f;
        const float w10 = (yv1 && xv0) ? gy1 * (1.f - fx) : 0.f;
        const float w11 = (yv1 && xv1) ? gy1 * fx         : 0.f;
        const int y0c = min(max(y0, 0), H_ - 1), y1c = min(max(y0 + 1, 0), H_ - 1);
        const int x0c = min(max(x0, 0), W_ - 1), x1c = min(max(x0 + 1, 0), W_ - 1);

        // params for next tap
        if (k < K2_ - 1) {
            npdy = offset[(n * 18 + 2 * (k + 1))     * (HO_ * WO_) + pofs];
            npdx = offset[(n * 18 + 2 * (k + 1) + 1) * (HO_ * WO_) + pofs];
            npm  = mask  [(n * 9  + (k + 1))         * (HO_ * WO_) + pofs];
        }

        // ---- 4 corners from LDS region (both ci halves), rare global fallback ----
        uint4 cva[4], cvb[4];   // [corner] kk=0 / kk=1
        const int cys[2] = { y0c, y1c };
        const int cxs[2] = { x0c, x1c };
#pragma unroll
        for (int cy_i = 0; cy_i < 2; ++cy_i) {
#pragma unroll
            for (int cx_i = 0; cx_i < 2; ++cx_i) {
                const int ci_ = cy_i * 2 + cx_i;
                const int cy = cys[cy_i], cx = cxs[cx_i];
                const int ry = cy - rowbase, rx = cx - colbase;
                const bool in = ((unsigned)ry < (unsigned)RROWS) &&
                                ((unsigned)rx < (unsigned)RCOLS);
                const int p = min(max(ry, 0), RROWS - 1) * RCOLS + min(max(rx, 0), RCOLS - 1);
                uint4 lv0 = *(const uint4*)(XrB + reg_byteoff(p, g));
                uint4 lv1 = *(const uint4*)(XrB + reg_byteoff(p, 4 + g));
                if (!__all((int)in)) {          // wave-uniform rare path
                    const unsigned short* gp = xb + (cy * W_ + cx) * CIN + ci0;
                    uint4 gv0 = *(const uint4*)(gp);
                    uint4 gv1 = *(const uint4*)(gp + 32);
                    if (!in) { lv0 = gv0; lv1 = gv1; }   // exec-masked per lane
                }
                cva[ci_] = lv0;
                cvb[ci_] = lv1;
            }
        }

        // ---- combine -> B fragments (bf16) ----
        union F8 { unsigned int u[4]; short8 s; } f0, f1;
        f0.u[0] = comb1(cva[0].x, cva[1].x, cva[2].x, cva[3].x, w00, w01, w10, w11);
        f0.u[1] = comb1(cva[0].y, cva[1].y, cva[2].y, cva[3].y, w00, w01, w10, w11);
        f0.u[2] = comb1(cva[0].z, cva[1].z, cva[2].z, cva[3].z, w00, w01, w10, w11);
        f0.u[3] = comb1(cva[0].w, cva[1].w, cva[2].w, cva[3].w, w00, w01, w10, w11);
        f1.u[0] = comb1(cvb[0].x, cvb[1].x, cvb[2].x, cvb[3].x, w00, w01, w10, w11);
        f1.u[1] = comb1(cvb[0].y, cvb[1].y, cvb[2].y, cvb[3].y, w00, w01, w10, w11);
        f1.u[2] = comb1(cvb[0].z, cvb[1].z, cvb[2].z, cvb[3].z, w00, w01, w10, w11);
        f1.u[3] = comb1(cvb[0].w, cvb[1].w, cvb[2].w, cvb[3].w, w00, w01, w10, w11);

        // ---- MFMA: 4 co-tiles x 2 k-halves ----
#pragma unroll
        for (int t = 0; t < 4; ++t) {
            const short8 A0 = Adbuf[k & 1][(t * 2 + 0) * 64 + lane];
            const short8 A1 = Adbuf[k & 1][(t * 2 + 1) * 64 + lane];
            acc[t] = __builtin_amdgcn_mfma_f32_16x16x32_bf16(A0, f0.s, acc[t], 0, 0, 0);
            acc[t] = __builtin_amdgcn_mfma_f32_16x16x32_bf16(A1, f1.s, acc[t], 0, 0, 0);
        }

        // write-late A-stage + single barrier per tap
        if (k < K2_ - 1) {
            Adbuf[(k + 1) & 1][tid] = sA;
            __syncthreads();
        }
    }

    // epilogue: D col = lane&15 (px/wo), row = g*4 + reg (co within tile t)
#pragma unroll
    for (int t = 0; t < 4; ++t) {
#pragma unroll
        for (int rr = 0; rr < 4; ++rr) {
            out[((size_t)(n * COUT + 16 * t + g * 4 + rr) * HO_ + ho) * WO_ + wo] = acc[t][rr];
        }
    }
}

// fp32 fallback (no workspace): known-correct round-1 structure.
__global__ __launch_bounds__(256, 4) void DeformConv2d_fallback(
    const float* __restrict__ x, const float* __restrict__ offset,
    const float* __restrict__ mask, const float* __restrict__ weight,
    float* __restrict__ out)
{
    __shared__ float W_lds[CIN * COUT];
    __shared__ float S_lds[CIN * 68];
    __shared__ float cfy[64], cfx[64], cm[64];
    __shared__ int   cy0[64], cx0[64];

    const int tid = threadIdx.x;
    const int raw = blockIdx.x;
    const int swz = (raw & 7) * 128 + (raw >> 3);
    const int n   = swz >> 8;
    const int r   = swz & 255;
    const int hb  = (r >> 3) << 2;
    const int wb  = (r & 7) << 4;
    const int tr = tid >> 4, tc = tid & 15;

    float acc[4][4];
#pragma unroll
    for (int j = 0; j < 4; ++j)
#pragma unroll
        for (int i = 0; i < 4; ++i) acc[j][i] = 0.f;

    for (int k = 0; k < K2_; ++k) {
        __syncthreads();
        if (tid < 64) {
            const int px = tid, ho = hb + (px >> 4), wo = wb + (px & 15);
            const int ki = k / 3, kj = k % 3;
            const float dy = offset[((n * 18 + 2 * k)     * HO_ + ho) * WO_ + wo];
            const float dx = offset[((n * 18 + 2 * k + 1) * HO_ + ho) * WO_ + wo];
            const float m  = mask  [((n * 9  + k)         * HO_ + ho) * WO_ + wo];
            const float yy = (float)(ho - 1 + ki) + dy;
            const float xx = (float)(wo - 1 + kj) + dx;
            const float y0f = floorf(yy), x0f = floorf(xx);
            cy0[px] = (int)y0f; cx0[px] = (int)x0f;
            cfy[px] = yy - y0f; cfx[px] = xx - x0f; cm[px] = m;
        }
#pragma unroll
        for (int e = 0; e < 16; ++e) {
            int i = e * 256 + tid, ci = i >> 6, co = i & 63;
            W_lds[ci * 64 + co] = weight[(co * CIN + ci) * K2_ + k];
        }
        __syncthreads();
#pragma unroll
        for (int e = 0; e < 16; ++e) {
            int i = e * 256 + tid, ci = i >> 6, px = i & 63;
            int   y0 = cy0[px], x0 = cx0[px];
            float fy = cfy[px], fx = cfx[px], m = cm[px];
            const float* xc = x + (size_t)(n * CIN + ci) * (H_ * W_);
            bool yv0 = (y0 >= 0)  && (y0 < H_);
            bool yv1 = (y0 >= -1) && (y0 < H_ - 1);
            bool xv0 = (x0 >= 0)  && (x0 < W_);
            bool xv1 = (x0 >= -1) && (x0 < W_ - 1);
            float v00 = (yv0 && xv0) ? xc[y0 * W_ + x0]           : 0.f;
            float v01 = (yv0 && xv1) ? xc[y0 * W_ + x0 + 1]       : 0.f;
            float v10 = (yv1 && xv0) ? xc[(y0 + 1) * W_ + x0]     : 0.f;
            float v11 = (yv1 && xv1) ? xc[(y0 + 1) * W_ + x0 + 1] : 0.f;
            float v = (v00 * (1.f - fy) + v10 * fy) * (1.f - fx)
                    + (v01 * (1.f - fy) + v11 * fy) * fx;
            S_lds[ci * 68 + px] = v * m;
        }
        __syncthreads();
#pragma unroll 8
        for (int ci = 0; ci < CIN; ++ci) {
            const float4 a = *(const float4*)&W_lds[ci * 64 + tr * 4];
            const float4 b = *(const float4*)&S_lds[ci * 68 + tc * 4];
            acc[0][0] += a.x * b.x; acc[0][1] += a.x * b.y; acc[0][2] += a.x * b.z; acc[0][3] += a.x * b.w;
            acc[1][0] += a.y * b.x; acc[1][1] += a.y * b.y; acc[1][2] += a.y * b.z; acc[1][3] += a.y * b.w;
            acc[2][0] += a.z * b.x; acc[2][1] += a.z * b.y; acc[2][2] += a.z * b.z; acc[2][3] += a.z * b.w;
            acc[3][0] += a.w * b.x; acc[3][1] += a.w * b.y; acc[3][2] += a.w * b.z; acc[3][3] += a.w * b.w;
        }
    }
    const int co0 = tr * 4, hoE = hb + (tc >> 2), woE = wb + (tc & 3) * 4;
#pragma unroll
    for (int j = 0; j < 4; ++j) {
        float4 v; v.x = acc[j][0]; v.y = acc[j][1]; v.z = acc[j][2]; v.w = acc[j][3];
        *(float4*)&out[((size_t)(n * COUT + co0 + j) * HO_ + hoE) * WO_ + woE] = v;
    }
}

extern "C" void kernel_launch(void* const* d_in, const int* in_sizes, int n_in,
                              void* d_out, int out_size, void* d_ws, size_t ws_size,
                              hipStream_t stream) {
    const float* x      = (const float*)d_in[0];
    const float* offset = (const float*)d_in[1];
    const float* mask   = (const float*)d_in[2];
    const float* weight = (const float*)d_in[3];
    float* out = (float*)d_out;

    const size_t wf_bytes = (size_t)K2_ * 8 * 64 * 8 * sizeof(unsigned short);        // 73728
    const size_t xt_bytes = (size_t)N_ * H_ * W_ * CIN * sizeof(unsigned short);      // 8 MB

    if (ws_size >= wf_bytes + xt_bytes) {
        unsigned short* wfb = (unsigned short*)d_ws;
        unsigned short* xtb = (unsigned short*)((char*)d_ws + wf_bytes);
        DeformConv2d_prep<<<4096 + 144, 256, 0, stream>>>(x, weight, xtb, wfb);
        DeformConv2d_mfma<<<512, 512, 0, stream>>>(offset, mask, wfb, xtb, out);
    } else {
        DeformConv2d_fallback<<<1024, 256, 0, stream>>>(x, offset, mask, weight, out);
    }
}